// Round 2
// baseline (850.290 us; speedup 1.0000x reference)
//
#include <hip/hip_runtime.h>

#define IN_DIM 128
#define HID    256
#define LAT    64

// ---------------------------------------------------------------------------
// Preprocessing kernels: GCN symmetric normalization + CSR-by-destination
// ---------------------------------------------------------------------------

__global__ void k_init(float* __restrict__ deg, int* __restrict__ counts, int n) {
    int i = blockIdx.x * 256 + threadIdx.x;
    if (i < n) { deg[i] = 1.0f; counts[i] = 0; }   // self-loop weight 1
}

__global__ void k_edge_deg(const int* __restrict__ ei, const float* __restrict__ ew,
                           float* __restrict__ deg, int* __restrict__ counts, int E) {
    int e = blockIdx.x * 256 + threadIdx.x;
    if (e < E) {
        int c = ei[E + e];                 // col
        atomicAdd(&deg[c], ew[e]);
        atomicAdd(&counts[c], 1);
    }
}

__global__ void k_dinv(const float* __restrict__ deg, float* __restrict__ dinv, int n) {
    int i = blockIdx.x * 256 + threadIdx.x;
    if (i < n) dinv[i] = rsqrtf(deg[i]);   // deg >= 1 always (self loop)
}

// Single-block exclusive scan over counts -> offsets[0..n], also copies to fillpos
__global__ __launch_bounds__(1024) void k_scan(const int* __restrict__ counts,
                                               int* __restrict__ offsets,
                                               int* __restrict__ fillpos, int n) {
    __shared__ int sums[1024];
    int t = threadIdx.x;
    int chunk = (n + 1023) / 1024;
    int start = t * chunk;
    int end   = min(start + chunk, n);
    int s = 0;
    for (int i = start; i < end; ++i) s += counts[i];
    sums[t] = s;
    __syncthreads();
    for (int d = 1; d < 1024; d <<= 1) {
        int v = (t >= d) ? sums[t - d] : 0;
        __syncthreads();
        sums[t] += v;
        __syncthreads();
    }
    int base = (t == 0) ? 0 : sums[t - 1];
    for (int i = start; i < end; ++i) {
        offsets[i] = base; fillpos[i] = base;
        base += counts[i];
    }
    if (t == 0) offsets[n] = sums[1023];
}

__global__ void k_fill(const int* __restrict__ ei, const float* __restrict__ ew,
                       const float* __restrict__ dinv, int* __restrict__ fillpos,
                       int* __restrict__ csr_row, float* __restrict__ csr_norm, int E) {
    int e = blockIdx.x * 256 + threadIdx.x;
    if (e < E) {
        int r = ei[e];
        int c = ei[E + e];
        int pos = atomicAdd(&fillpos[c], 1);
        csr_row[pos]  = r;
        csr_norm[pos] = dinv[r] * ew[e] * dinv[c];
    }
}

// ---------------------------------------------------------------------------
// fp32 GEMM: C[M,F] = A[M,K] @ W[K,F].
// BM=128, BN=64*NSUB, BK=32; 256 threads; each thread: 2 x NSUB sub-blocks of 4x4.
// Sub-block offsets {ty*4, 64+ty*4} x {tx*4, 64+tx*4} keep LDS reads <=2-way.
// K divisible by 32, F divisible by 64.
// ---------------------------------------------------------------------------
template <int NSUB>
__global__ __launch_bounds__(256) void gemm_f32(const float* __restrict__ A,
                                                const float* __restrict__ W,
                                                float* __restrict__ C,
                                                int M, int K, int F) {
    constexpr int BN = 64 * NSUB;
    __shared__ alignas(16) float As[32][132];   // [k][m] transposed; 132: rows stay 16B aligned
    __shared__ alignas(16) float Ws[32][BN];    // [k][n]
    const int bm  = blockIdx.x * 128;
    const int bn  = blockIdx.y * BN;
    const int tid = threadIdx.x;
    const int ty  = tid >> 4;      // 0..15
    const int tx  = tid & 15;      // 0..15
    float acc[2][NSUB][4][4] = {};
    for (int k0 = 0; k0 < K; k0 += 32) {
        __syncthreads();
        // A tile: 128 rows x 32 k (1024 float4 loads, 4 per thread), transpose into As
        #pragma unroll
        for (int it = 0; it < 4; ++it) {
            int l   = tid + it * 256;
            int row = l >> 3;          // 0..127
            int k4  = l & 7;           // 0..7
            int gr  = bm + row;
            float4 v = make_float4(0.f, 0.f, 0.f, 0.f);
            if (gr < M) v = *(const float4*)&A[(size_t)gr * K + k0 + k4 * 4];
            As[k4 * 4 + 0][row] = v.x;
            As[k4 * 4 + 1][row] = v.y;
            As[k4 * 4 + 2][row] = v.z;
            As[k4 * 4 + 3][row] = v.w;
        }
        // W tile: 32 k x BN cols (BN*8 float4 loads)
        #pragma unroll
        for (int it = 0; it < NSUB * 2; ++it) {
            int l  = tid + it * 256;
            int kk = l / (BN / 4);
            int c4 = l % (BN / 4);
            *(float4*)&Ws[kk][c4 * 4] =
                *(const float4*)&W[(size_t)(k0 + kk) * F + bn + c4 * 4];
        }
        __syncthreads();
        #pragma unroll
        for (int kk = 0; kk < 32; ++kk) {
            float4 a0 = *(const float4*)&As[kk][ty * 4];
            float4 a1 = *(const float4*)&As[kk][64 + ty * 4];
            float am[2][4] = {{a0.x, a0.y, a0.z, a0.w}, {a1.x, a1.y, a1.z, a1.w}};
            #pragma unroll
            for (int ns = 0; ns < NSUB; ++ns) {
                float4 w4 = *(const float4*)&Ws[kk][ns * 64 + tx * 4];
                float wn[4] = {w4.x, w4.y, w4.z, w4.w};
                #pragma unroll
                for (int ms = 0; ms < 2; ++ms)
                    #pragma unroll
                    for (int i = 0; i < 4; ++i)
                        #pragma unroll
                        for (int j = 0; j < 4; ++j)
                            acc[ms][ns][i][j] = fmaf(am[ms][i], wn[j], acc[ms][ns][i][j]);
            }
        }
    }
    #pragma unroll
    for (int ms = 0; ms < 2; ++ms)
        #pragma unroll
        for (int i = 0; i < 4; ++i) {
            int gr = bm + ms * 64 + ty * 4 + i;
            if (gr >= M) continue;
            #pragma unroll
            for (int ns = 0; ns < NSUB; ++ns)
                *(float4*)&C[(size_t)gr * F + bn + ns * 64 + tx * 4] =
                    make_float4(acc[ms][ns][i][0], acc[ms][ns][i][1],
                                acc[ms][ns][i][2], acc[ms][ns][i][3]);
        }
}

// ---------------------------------------------------------------------------
// Aggregation: out[c] = selfnorm*pre[c] + sum_{e: col=c} norm_e * pre[row_e] + b
// One wave per node, lane-vectorized (F = VEC*64). Optional fused ReLU.
// ---------------------------------------------------------------------------

template <int VEC>
__device__ __forceinline__ void vload(float* d, const float* s) {
    if constexpr (VEC == 4) { float4 v = *(const float4*)s; d[0]=v.x; d[1]=v.y; d[2]=v.z; d[3]=v.w; }
    else if constexpr (VEC == 2) { float2 v = *(const float2*)s; d[0]=v.x; d[1]=v.y; }
    else { d[0] = *s; }
}
template <int VEC>
__device__ __forceinline__ void vstore(float* d, const float* s) {
    if constexpr (VEC == 4) { *(float4*)d = make_float4(s[0], s[1], s[2], s[3]); }
    else if constexpr (VEC == 2) { *(float2*)d = make_float2(s[0], s[1]); }
    else { *d = s[0]; }
}

template <int VEC, bool RELU>
__global__ __launch_bounds__(256) void agg_kernel(
    const float* __restrict__ pre, const float* __restrict__ bias,
    const int* __restrict__ offsets, const int* __restrict__ csr_row,
    const float* __restrict__ csr_norm, const float* __restrict__ dinv,
    float* __restrict__ out, int n) {
    constexpr int F = VEC * 64;
    const int wave = threadIdx.x >> 6;
    const int lane = threadIdx.x & 63;
    const int c = blockIdx.x * 4 + wave;
    if (c >= n) return;
    const float di = dinv[c];
    const float sn = di * di;      // self-loop norm (weight 1)
    float acc[VEC], t0[VEC], t1[VEC], bv[VEC];
    vload<VEC>(acc, pre + (size_t)c * F + lane * VEC);
    #pragma unroll
    for (int v = 0; v < VEC; ++v) acc[v] *= sn;
    const int beg = offsets[c], end = offsets[c + 1];
    int j = beg;
    for (; j + 1 < end; j += 2) {
        int   r0 = csr_row[j],     r1 = csr_row[j + 1];
        float w0 = csr_norm[j],    w1 = csr_norm[j + 1];
        vload<VEC>(t0, pre + (size_t)r0 * F + lane * VEC);
        vload<VEC>(t1, pre + (size_t)r1 * F + lane * VEC);
        #pragma unroll
        for (int v = 0; v < VEC; ++v) acc[v] = fmaf(w0, t0[v], acc[v]);
        #pragma unroll
        for (int v = 0; v < VEC; ++v) acc[v] = fmaf(w1, t1[v], acc[v]);
    }
    if (j < end) {
        int r0 = csr_row[j]; float w0 = csr_norm[j];
        vload<VEC>(t0, pre + (size_t)r0 * F + lane * VEC);
        #pragma unroll
        for (int v = 0; v < VEC; ++v) acc[v] = fmaf(w0, t0[v], acc[v]);
    }
    vload<VEC>(bv, bias + lane * VEC);
    #pragma unroll
    for (int v = 0; v < VEC; ++v) {
        float o = acc[v] + bv[v];
        if (RELU) o = fmaxf(o, 0.f);
        acc[v] = o;
    }
    vstore<VEC>(out + (size_t)c * F + lane * VEC, acc);
}

// ---------------------------------------------------------------------------

extern "C" void kernel_launch(void* const* d_in, const int* in_sizes, int n_in,
                              void* d_out, int out_size, void* d_ws, size_t ws_size,
                              hipStream_t stream) {
    const float* x  = (const float*)d_in[0];
    const int*   ei = (const int*)  d_in[1];   // [2,E] int32
    const float* ew = (const float*)d_in[2];
    const float* W1 = (const float*)d_in[3];
    const float* b1 = (const float*)d_in[4];
    const float* W2 = (const float*)d_in[5];
    const float* b2 = (const float*)d_in[6];
    const float* W3 = (const float*)d_in[7];
    const float* b3 = (const float*)d_in[8];
    const float* W4 = (const float*)d_in[9];
    const float* b4 = (const float*)d_in[10];

    const int N = in_sizes[0] / IN_DIM;
    const int E = in_sizes[2];

    // workspace carve-up (256B aligned slices)
    char* p = (char*)d_ws;
    auto alloc = [&](size_t bytes) -> void* {
        void* r = (void*)p;
        p += (bytes + 255) & ~(size_t)255;
        return r;
    };
    float* deg      = (float*)alloc((size_t)N * 4);
    float* dinv     = (float*)alloc((size_t)N * 4);
    int*   counts   = (int*)  alloc((size_t)N * 4);
    int*   offsets  = (int*)  alloc((size_t)(N + 1) * 4);
    int*   fillpos  = (int*)  alloc((size_t)N * 4);
    int*   csr_row  = (int*)  alloc((size_t)E * 4);
    float* csr_norm = (float*)alloc((size_t)E * 4);
    float* bufA     = (float*)alloc((size_t)N * HID * 4);   // GEMM outputs (max width 256)
    float* bufB     = (float*)alloc((size_t)N * HID * 4);   // activations (width 256)
    float* bufC     = (float*)alloc((size_t)N * LAT * 4);   // latent z (width 64)

    const int gN = (N + 255) / 256;
    const int gE = (E + 255) / 256;
    const int nbM = (N + 127) / 128;
    const int nodeBlocks = (N + 3) / 4;

    // --- normalization + CSR build ---
    k_init    <<<gN, 256, 0, stream>>>(deg, counts, N);
    k_edge_deg<<<gE, 256, 0, stream>>>(ei, ew, deg, counts, E);
    k_dinv    <<<gN, 256, 0, stream>>>(deg, dinv, N);
    k_scan    <<<1, 1024, 0, stream>>>(counts, offsets, fillpos, N);
    k_fill    <<<gE, 256, 0, stream>>>(ei, ew, dinv, fillpos, csr_row, csr_norm, E);

    // --- layer 1: x @ W1 -> agg+b1+relu ---
    gemm_f32<2><<<dim3(nbM, HID / 128), 256, 0, stream>>>(x, W1, bufA, N, IN_DIM, HID);
    agg_kernel<4, true><<<nodeBlocks, 256, 0, stream>>>(bufA, b1, offsets, csr_row, csr_norm, dinv, bufB, N);

    // --- layer 2: h1 @ W2 -> agg+b2 (latent) ---
    gemm_f32<1><<<dim3(nbM, LAT / 64), 256, 0, stream>>>(bufB, W2, bufA, N, HID, LAT);
    agg_kernel<1, false><<<nodeBlocks, 256, 0, stream>>>(bufA, b2, offsets, csr_row, csr_norm, dinv, bufC, N);

    // --- layer 3: z @ W3 -> agg+b3+relu ---
    gemm_f32<2><<<dim3(nbM, HID / 128), 256, 0, stream>>>(bufC, W3, bufA, N, LAT, HID);
    agg_kernel<4, true><<<nodeBlocks, 256, 0, stream>>>(bufA, b3, offsets, csr_row, csr_norm, dinv, bufB, N);

    // --- layer 4: h3 @ W4 -> agg+b4 -> d_out ---
    gemm_f32<2><<<dim3(nbM, IN_DIM / 128), 256, 0, stream>>>(bufB, W4, bufA, N, HID, IN_DIM);
    agg_kernel<2, false><<<nodeBlocks, 256, 0, stream>>>(bufA, b4, offsets, csr_row, csr_norm, dinv, (float*)d_out, N);
}

// Round 4
// 671.874 us; speedup vs baseline: 1.2655x; 1.2655x over previous
//
#include <hip/hip_runtime.h>
#include <hip/hip_fp16.h>

#define IN_DIM 128
#define HID    256
#define LAT    64

typedef __attribute__((ext_vector_type(8))) short bf16x8;
typedef __attribute__((ext_vector_type(4))) float f32x4;

// ---------------------------------------------------------------------------
// bf16 split helpers (round-to-nearest-even)
// ---------------------------------------------------------------------------
__device__ __forceinline__ short f2bf(float f) {
    union { float f; unsigned u; } v; v.f = f;
    unsigned r = v.u + 0x7fffu + ((v.u >> 16) & 1u);
    return (short)(r >> 16);
}
__device__ __forceinline__ float bf2f(short s) {
    union { unsigned u; float f; } v; v.u = ((unsigned)(unsigned short)s) << 16;
    return v.f;
}

// P-store overloads (f16 for inner layers, fp32 for the output layer)
__device__ __forceinline__ void storeP(__half* p, float v) { *p = __float2half(v); }
__device__ __forceinline__ void storeP(float*  p, float v) { *p = v; }

// ---------------------------------------------------------------------------
// Preprocessing: GCN symmetric normalization + CSR-by-destination
// ---------------------------------------------------------------------------

__global__ void k_init(float* __restrict__ deg, int* __restrict__ counts, int n) {
    int i = blockIdx.x * 256 + threadIdx.x;
    if (i < n) { deg[i] = 1.0f; counts[i] = 0; }   // self-loop weight 1
}

__global__ void k_edge_deg(const int* __restrict__ ei, const float* __restrict__ ew,
                           float* __restrict__ deg, int* __restrict__ counts, int E) {
    int e = blockIdx.x * 256 + threadIdx.x;
    if (e < E) {
        int c = ei[E + e];
        atomicAdd(&deg[c], ew[e]);
        atomicAdd(&counts[c], 1);
    }
}

__global__ void k_dinv(const float* __restrict__ deg, float* __restrict__ dinv, int n) {
    int i = blockIdx.x * 256 + threadIdx.x;
    if (i < n) dinv[i] = rsqrtf(deg[i]);
}

__global__ __launch_bounds__(1024) void k_scan(const int* __restrict__ counts,
                                               int* __restrict__ offsets,
                                               int* __restrict__ fillpos, int n) {
    __shared__ int sums[1024];
    int t = threadIdx.x;
    int chunk = (n + 1023) / 1024;
    int start = t * chunk;
    int end   = min(start + chunk, n);
    int s = 0;
    for (int i = start; i < end; ++i) s += counts[i];
    sums[t] = s;
    __syncthreads();
    for (int d = 1; d < 1024; d <<= 1) {
        int v = (t >= d) ? sums[t - d] : 0;
        __syncthreads();
        sums[t] += v;
        __syncthreads();
    }
    int base = (t == 0) ? 0 : sums[t - 1];
    for (int i = start; i < end; ++i) {
        offsets[i] = base; fillpos[i] = base;
        base += counts[i];
    }
    if (t == 0) offsets[n] = sums[1023];
}

__global__ void k_fill(const int* __restrict__ ei, const float* __restrict__ ew,
                       const float* __restrict__ dinv, int* __restrict__ fillpos,
                       int* __restrict__ csr_row, float* __restrict__ csr_norm, int E) {
    int e = blockIdx.x * 256 + threadIdx.x;
    if (e < E) {
        int r = ei[e];
        int c = ei[E + e];
        int pos = atomicAdd(&fillpos[c], 1);
        csr_row[pos]  = r;
        csr_norm[pos] = dinv[r] * ew[e] * dinv[c];
    }
}

// ---------------------------------------------------------------------------
// MFMA GEMM with bf16 Markidis split: P[M,F] = A_f32[M,K] @ W_f32[K,F].
// BM=128, BK=32, BN template (64 or 128). 256 threads = 4 waves in 2x2 grid.
// LDS tiles row-pitch 40 bf16 (80B): fragment reads are <=2-way (free, m136).
// 3 MFMAs per fragment pair: hi*hi + hi*lo + lo*hi (error ~2^-16 relative).
// K % 32 == 0 required. PT = __half (inner layers) or float (output layer).
// ---------------------------------------------------------------------------
template <int BN, typename PT>
__global__ __launch_bounds__(256) void gemm_mfma(const float* __restrict__ A,
                                                 const float* __restrict__ W,
                                                 PT* __restrict__ P,
                                                 int M, int K, int F) {
    constexpr int WC = BN / 32;          // col fragments per wave
    __shared__ alignas(16) short Ahi[128][40];
    __shared__ alignas(16) short Alo[128][40];
    __shared__ alignas(16) short Whi[BN][40];
    __shared__ alignas(16) short Wlo[BN][40];

    const int bm  = blockIdx.x * 128;
    const int bn  = blockIdx.y * BN;
    const int tid = threadIdx.x;
    const int wv  = tid >> 6;
    const int wy  = wv >> 1;             // 0..1 : row half
    const int wx  = wv & 1;              // 0..1 : col half
    const int lane = tid & 63;
    const int frow = lane & 15;          // fragment row (A) / col (B)
    const int fk   = (lane >> 4) * 8;    // fragment k offset (elements)

    // W staging coords
    const int wc_ = tid % BN;            // column within tile
    const int kg  = tid / BN;            // k group
    constexpr int KC = 32 * BN / 256;    // k elems per thread (16 or 8)

    f32x4 acc[4][WC];
    #pragma unroll
    for (int i = 0; i < 4; ++i)
        #pragma unroll
        for (int j = 0; j < WC; ++j)
            acc[i][j] = (f32x4){0.f, 0.f, 0.f, 0.f};

    for (int k0 = 0; k0 < K; k0 += 32) {
        if (k0) __syncthreads();
        // --- stage A: 128 rows x 32 k, float4 global loads, split to hi/lo ---
        #pragma unroll
        for (int it = 0; it < 4; ++it) {
            int l   = tid + it * 256;     // 0..1023
            int row = l >> 3;
            int k4  = l & 7;
            int gr  = bm + row;
            float4 v = make_float4(0.f, 0.f, 0.f, 0.f);
            if (gr < M) v = *(const float4*)&A[(size_t)gr * K + k0 + k4 * 4];
            float vv[4] = {v.x, v.y, v.z, v.w};
            short h[4], lo[4];
            #pragma unroll
            for (int j = 0; j < 4; ++j) {
                h[j]  = f2bf(vv[j]);
                lo[j] = f2bf(vv[j] - bf2f(h[j]));
            }
            *(short4*)&Ahi[row][k4 * 4] = make_short4(h[0], h[1], h[2], h[3]);
            *(short4*)&Alo[row][k4 * 4] = make_short4(lo[0], lo[1], lo[2], lo[3]);
        }
        // --- stage W transposed: Wt[col][k], scalar loads (coalesced in wc_) ---
        #pragma unroll
        for (int kk = 0; kk < KC; kk += 4) {
            short h[4], lo[4];
            #pragma unroll
            for (int j = 0; j < 4; ++j) {
                float w = W[(size_t)(k0 + kg * KC + kk + j) * F + bn + wc_];
                h[j]  = f2bf(w);
                lo[j] = f2bf(w - bf2f(h[j]));
            }
            *(short4*)&Whi[wc_][kg * KC + kk] = make_short4(h[0], h[1], h[2], h[3]);
            *(short4*)&Wlo[wc_][kg * KC + kk] = make_short4(lo[0], lo[1], lo[2], lo[3]);
        }
        __syncthreads();
        // --- fragments + MFMA ---
        bf16x8 ah[4], al[4], wh[WC], wl[WC];
        #pragma unroll
        for (int ar = 0; ar < 4; ++ar) {
            ah[ar] = *(const bf16x8*)&Ahi[wy * 64 + ar * 16 + frow][fk];
            al[ar] = *(const bf16x8*)&Alo[wy * 64 + ar * 16 + frow][fk];
        }
        #pragma unroll
        for (int wc = 0; wc < WC; ++wc) {
            wh[wc] = *(const bf16x8*)&Whi[wx * (BN / 2) + wc * 16 + frow][fk];
            wl[wc] = *(const bf16x8*)&Wlo[wx * (BN / 2) + wc * 16 + frow][fk];
        }
        #pragma unroll
        for (int ar = 0; ar < 4; ++ar)
            #pragma unroll
            for (int wc = 0; wc < WC; ++wc) {
                acc[ar][wc] = __builtin_amdgcn_mfma_f32_16x16x32_bf16(ah[ar], wh[wc], acc[ar][wc], 0, 0, 0);
                acc[ar][wc] = __builtin_amdgcn_mfma_f32_16x16x32_bf16(ah[ar], wl[wc], acc[ar][wc], 0, 0, 0);
                acc[ar][wc] = __builtin_amdgcn_mfma_f32_16x16x32_bf16(al[ar], wh[wc], acc[ar][wc], 0, 0, 0);
            }
    }
    // --- store P; C/D layout: col=lane&15, row=(lane>>4)*4+reg (m89) ---
    #pragma unroll
    for (int ar = 0; ar < 4; ++ar)
        #pragma unroll
        for (int r = 0; r < 4; ++r) {
            int row = bm + wy * 64 + ar * 16 + (lane >> 4) * 4 + r;
            if (row >= M) continue;
            #pragma unroll
            for (int wc = 0; wc < WC; ++wc) {
                int col = bn + wx * (BN / 2) + wc * 16 + (lane & 15);
                storeP(&P[(size_t)row * F + col], acc[ar][wc][r]);
            }
        }
}

// ---------------------------------------------------------------------------
// Aggregation: out[c] = sn*P[c] + sum_e norm_e * P[row_e] + b
// One wave per node, lane-vectorized (F = VEC*64). fp32 accumulate/output.
// PT = __half or float.
// ---------------------------------------------------------------------------

template <int VEC>
__device__ __forceinline__ void pload(float* d, const __half* s) {
    if constexpr (VEC == 4) {
        union { short4 s4; __half h[4]; } u;
        u.s4 = *(const short4*)s;
        #pragma unroll
        for (int j = 0; j < 4; ++j) d[j] = __half2float(u.h[j]);
    } else if constexpr (VEC == 2) {
        union { short2 s2; __half h[2]; } u;
        u.s2 = *(const short2*)s;
        d[0] = __half2float(u.h[0]); d[1] = __half2float(u.h[1]);
    } else {
        d[0] = __half2float(*s);
    }
}
template <int VEC>
__device__ __forceinline__ void pload(float* d, const float* s) {
    if constexpr (VEC == 4) { float4 v = *(const float4*)s; d[0]=v.x; d[1]=v.y; d[2]=v.z; d[3]=v.w; }
    else if constexpr (VEC == 2) { float2 v = *(const float2*)s; d[0]=v.x; d[1]=v.y; }
    else { d[0] = *s; }
}
template <int VEC>
__device__ __forceinline__ void fstore(float* d, const float* s) {
    if constexpr (VEC == 4) { *(float4*)d = make_float4(s[0], s[1], s[2], s[3]); }
    else if constexpr (VEC == 2) { *(float2*)d = make_float2(s[0], s[1]); }
    else { *d = s[0]; }
}

template <int VEC, bool RELU, typename PT>
__global__ __launch_bounds__(256) void agg_kernel(
    const PT* __restrict__ pre, const float* __restrict__ bias,
    const int* __restrict__ offsets, const int* __restrict__ csr_row,
    const float* __restrict__ csr_norm, const float* __restrict__ dinv,
    float* __restrict__ out, int n) {
    constexpr int F = VEC * 64;
    const int wave = threadIdx.x >> 6;
    const int lane = threadIdx.x & 63;
    const int c = blockIdx.x * 4 + wave;
    if (c >= n) return;
    const float di = dinv[c];
    const float sn = di * di;
    float acc[VEC], t0[VEC], t1[VEC], bv[VEC];
    pload<VEC>(acc, pre + (size_t)c * F + lane * VEC);
    #pragma unroll
    for (int v = 0; v < VEC; ++v) acc[v] *= sn;
    const int beg = offsets[c], end = offsets[c + 1];
    int j = beg;
    for (; j + 1 < end; j += 2) {
        int   r0 = csr_row[j],  r1 = csr_row[j + 1];
        float w0 = csr_norm[j], w1 = csr_norm[j + 1];
        pload<VEC>(t0, pre + (size_t)r0 * F + lane * VEC);
        pload<VEC>(t1, pre + (size_t)r1 * F + lane * VEC);
        #pragma unroll
        for (int v = 0; v < VEC; ++v) acc[v] = fmaf(w0, t0[v], acc[v]);
        #pragma unroll
        for (int v = 0; v < VEC; ++v) acc[v] = fmaf(w1, t1[v], acc[v]);
    }
    if (j < end) {
        int r0 = csr_row[j]; float w0 = csr_norm[j];
        pload<VEC>(t0, pre + (size_t)r0 * F + lane * VEC);
        #pragma unroll
        for (int v = 0; v < VEC; ++v) acc[v] = fmaf(w0, t0[v], acc[v]);
    }
    pload<VEC>(bv, bias + lane * VEC);
    #pragma unroll
    for (int v = 0; v < VEC; ++v) {
        float o = acc[v] + bv[v];
        if (RELU) o = fmaxf(o, 0.f);
        acc[v] = o;
    }
    fstore<VEC>(out + (size_t)c * F + lane * VEC, acc);
}

// ---------------------------------------------------------------------------

extern "C" void kernel_launch(void* const* d_in, const int* in_sizes, int n_in,
                              void* d_out, int out_size, void* d_ws, size_t ws_size,
                              hipStream_t stream) {
    const float* x  = (const float*)d_in[0];
    const int*   ei = (const int*)  d_in[1];   // [2,E] int32
    const float* ew = (const float*)d_in[2];
    const float* W1 = (const float*)d_in[3];
    const float* b1 = (const float*)d_in[4];
    const float* W2 = (const float*)d_in[5];
    const float* b2 = (const float*)d_in[6];
    const float* W3 = (const float*)d_in[7];
    const float* b3 = (const float*)d_in[8];
    const float* W4 = (const float*)d_in[9];
    const float* b4 = (const float*)d_in[10];

    const int N = in_sizes[0] / IN_DIM;
    const int E = in_sizes[2];

    char* p = (char*)d_ws;
    auto alloc = [&](size_t bytes) -> void* {
        void* r = (void*)p;
        p += (bytes + 255) & ~(size_t)255;
        return r;
    };
    float*  deg      = (float*)alloc((size_t)N * 4);
    float*  dinv     = (float*)alloc((size_t)N * 4);
    int*    counts   = (int*)  alloc((size_t)N * 4);
    int*    offsets  = (int*)  alloc((size_t)(N + 1) * 4);
    int*    fillpos  = (int*)  alloc((size_t)N * 4);
    int*    csr_row  = (int*)  alloc((size_t)E * 4);
    float*  csr_norm = (float*)alloc((size_t)E * 4);
    __half* bufP     = (__half*)alloc((size_t)N * HID * 2);  // GEMM out (f16, width<=256)
    float*  bufH     = (float*) alloc((size_t)N * HID * 4);  // agg out (fp32, width 256)
    float*  bufZ     = (float*) alloc((size_t)N * LAT * 4);  // latent (fp32, width 64)
    // layer-4 fp32 P aliases bufP exactly: N*256*2 bytes == N*128*4 bytes
    float*  bufP32   = (float*)bufP;

    const int gN = (N + 255) / 256;
    const int gE = (E + 255) / 256;
    const int nbM = (N + 127) / 128;
    const int nodeBlocks = (N + 3) / 4;

    // --- normalization + CSR build ---
    k_init    <<<gN, 256, 0, stream>>>(deg, counts, N);
    k_edge_deg<<<gE, 256, 0, stream>>>(ei, ew, deg, counts, E);
    k_dinv    <<<gN, 256, 0, stream>>>(deg, dinv, N);
    k_scan    <<<1, 1024, 0, stream>>>(counts, offsets, fillpos, N);
    k_fill    <<<gE, 256, 0, stream>>>(ei, ew, dinv, fillpos, csr_row, csr_norm, E);

    // --- layer 1: x @ W1 -> agg+b1+relu ---
    gemm_mfma<128, __half><<<dim3(nbM, HID / 128), 256, 0, stream>>>(x, W1, bufP, N, IN_DIM, HID);
    agg_kernel<4, true, __half><<<nodeBlocks, 256, 0, stream>>>(bufP, b1, offsets, csr_row, csr_norm, dinv, bufH, N);

    // --- layer 2: h1 @ W2 -> agg+b2 (latent) ---
    gemm_mfma<64, __half><<<dim3(nbM, LAT / 64), 256, 0, stream>>>(bufH, W2, bufP, N, HID, LAT);
    agg_kernel<1, false, __half><<<nodeBlocks, 256, 0, stream>>>(bufP, b2, offsets, csr_row, csr_norm, dinv, bufZ, N);

    // --- layer 3: z @ W3 -> agg+b3+relu ---
    gemm_mfma<128, __half><<<dim3(nbM, HID / 128), 256, 0, stream>>>(bufZ, W3, bufP, N, LAT, HID);
    agg_kernel<4, true, __half><<<nodeBlocks, 256, 0, stream>>>(bufP, b3, offsets, csr_row, csr_norm, dinv, bufH, N);

    // --- layer 4: h3 @ W4 -> agg+b4 -> d_out (fp32 P: high-sn nodes see fp32 error) ---
    gemm_mfma<128, float><<<dim3(nbM, IN_DIM / 128), 256, 0, stream>>>(bufH, W4, bufP32, N, HID, IN_DIM);
    agg_kernel<2, false, float><<<nodeBlocks, 256, 0, stream>>>(bufP32, b4, offsets, csr_row, csr_norm, dinv, (float*)d_out, N);
}

// Round 5
// 546.394 us; speedup vs baseline: 1.5562x; 1.2297x over previous
//
#include <hip/hip_runtime.h>
#include <hip/hip_fp16.h>

#define IN_DIM 128
#define HID    256
#define LAT    64

typedef __attribute__((ext_vector_type(8))) short bf16x8;
typedef __attribute__((ext_vector_type(4))) float f32x4;

// ---------------------------------------------------------------------------
// bf16 split helpers (round-to-nearest-even)
// ---------------------------------------------------------------------------
__device__ __forceinline__ short f2bf(float f) {
    union { float f; unsigned u; } v; v.f = f;
    unsigned r = v.u + 0x7fffu + ((v.u >> 16) & 1u);
    return (short)(r >> 16);
}
__device__ __forceinline__ float bf2f(short s) {
    union { unsigned u; float f; } v; v.u = ((unsigned)(unsigned short)s) << 16;
    return v.f;
}

__device__ __forceinline__ void storeP(__half* p, float v) { *p = __float2half(v); }
__device__ __forceinline__ void storeP(float*  p, float v) { *p = v; }

// ---------------------------------------------------------------------------
// Preprocessing: GCN symmetric normalization + CSR-by-destination
// ---------------------------------------------------------------------------

__global__ void k_init(float* __restrict__ deg, int* __restrict__ counts, int n) {
    int i = blockIdx.x * 256 + threadIdx.x;
    if (i < n) { deg[i] = 1.0f; counts[i] = 0; }   // self-loop weight 1
}

__global__ void k_edge_deg(const int* __restrict__ ei, const float* __restrict__ ew,
                           float* __restrict__ deg, int* __restrict__ counts, int E) {
    int e = blockIdx.x * 256 + threadIdx.x;
    if (e < E) {
        int c = ei[E + e];
        atomicAdd(&deg[c], ew[e]);
        atomicAdd(&counts[c], 1);
    }
}

__global__ void k_dinv(const float* __restrict__ deg, float* __restrict__ dinv, int n) {
    int i = blockIdx.x * 256 + threadIdx.x;
    if (i < n) dinv[i] = rsqrtf(deg[i]);
}

// --- coalesced 3-phase exclusive scan (n <= 64*1024) ---
// phase 1: per-block (1024-wide) totals
__global__ __launch_bounds__(1024) void k_blocksum(const int* __restrict__ counts,
                                                   int* __restrict__ bsum, int n) {
    __shared__ int ws[16];
    const int t = threadIdx.x, lane = t & 63, wv = t >> 6;
    int i = blockIdx.x * 1024 + t;
    int v = (i < n) ? counts[i] : 0;
    #pragma unroll
    for (int d = 1; d < 64; d <<= 1) v += __shfl_xor(v, d);
    if (lane == 0) ws[wv] = v;
    __syncthreads();
    if (wv == 0 && lane < 16) {
        int x = ws[lane];
        #pragma unroll
        for (int d = 1; d < 16; d <<= 1) x += __shfl_xor(x, d, 16);
        if (lane == 0) bsum[blockIdx.x] = x;
    }
}

// phase 2: single-wave inclusive scan over block sums (nb <= 64); writes total
__global__ void k_scan_bsums(int* __restrict__ bsum, int nb,
                             int* __restrict__ offsets, int n) {
    int lane = threadIdx.x;          // 64 threads
    int v = (lane < nb) ? bsum[lane] : 0;
    #pragma unroll
    for (int d = 1; d < 64; d <<= 1) {
        int u = __shfl_up(v, d);
        if (lane >= d) v += u;
    }
    if (lane < nb) bsum[lane] = v;   // inclusive
    if (lane == nb - 1) offsets[n] = v;
}

// phase 3: per-block scan + scanned block base -> exclusive offsets
__global__ __launch_bounds__(1024) void k_scan_apply(const int* __restrict__ counts,
                                                     const int* __restrict__ bsum,
                                                     int* __restrict__ offsets,
                                                     int* __restrict__ fillpos, int n) {
    __shared__ int ws[16];
    const int t = threadIdx.x, lane = t & 63, wv = t >> 6;
    int i = blockIdx.x * 1024 + t;
    int v = (i < n) ? counts[i] : 0;
    int s = v;
    #pragma unroll
    for (int d = 1; d < 64; d <<= 1) {
        int u = __shfl_up(s, d);
        if (lane >= d) s += u;
    }
    if (lane == 63) ws[wv] = s;
    __syncthreads();
    if (wv == 0 && lane < 16) {
        int x = ws[lane];
        #pragma unroll
        for (int d = 1; d < 16; d <<= 1) {
            int u = __shfl_up(x, d, 16);
            if (lane >= d) x += u;
        }
        ws[lane] = x;
    }
    __syncthreads();
    int base = (blockIdx.x ? bsum[blockIdx.x - 1] : 0) + (wv ? ws[wv - 1] : 0);
    int excl = base + s - v;
    if (i < n) { offsets[i] = excl; fillpos[i] = excl; }
}

__global__ void k_fill(const int* __restrict__ ei, const float* __restrict__ ew,
                       const float* __restrict__ dinv, int* __restrict__ fillpos,
                       int* __restrict__ csr_row, float* __restrict__ csr_norm, int E) {
    int e = blockIdx.x * 256 + threadIdx.x;
    if (e < E) {
        int r = ei[e];
        int c = ei[E + e];
        int pos = atomicAdd(&fillpos[c], 1);
        csr_row[pos]  = r;
        csr_norm[pos] = dinv[r] * ew[e] * dinv[c];
    }
}

// ---------------------------------------------------------------------------
// MFMA GEMM with bf16 Markidis split: P[M,F] = A_f32[M,K] @ W_f32[K,F].
// BM=128, BK=32, BN template (64 or 128). 256 threads = 4 waves in 2x2 grid.
// LDS tiles row-pitch 40 bf16 (80B): fragment reads are <=2-way (free, m136).
// 3 MFMAs per fragment pair: hi*hi + hi*lo + lo*hi (error ~2^-16 relative).
// K % 32 == 0 required. PT = __half (inner layers) or float (output layer).
// ---------------------------------------------------------------------------
template <int BN, typename PT>
__global__ __launch_bounds__(256) void gemm_mfma(const float* __restrict__ A,
                                                 const float* __restrict__ W,
                                                 PT* __restrict__ P,
                                                 int M, int K, int F) {
    constexpr int WC = BN / 32;          // col fragments per wave
    __shared__ alignas(16) short Ahi[128][40];
    __shared__ alignas(16) short Alo[128][40];
    __shared__ alignas(16) short Whi[BN][40];
    __shared__ alignas(16) short Wlo[BN][40];

    const int bm  = blockIdx.x * 128;
    const int bn  = blockIdx.y * BN;
    const int tid = threadIdx.x;
    const int wv  = tid >> 6;
    const int wy  = wv >> 1;             // 0..1 : row half
    const int wx  = wv & 1;              // 0..1 : col half
    const int lane = tid & 63;
    const int frow = lane & 15;          // fragment row (A) / col (B)
    const int fk   = (lane >> 4) * 8;    // fragment k offset (elements)

    const int wc_ = tid % BN;            // column within tile
    const int kg  = tid / BN;            // k group
    constexpr int KC = 32 * BN / 256;    // k elems per thread (16 or 8)

    f32x4 acc[4][WC];
    #pragma unroll
    for (int i = 0; i < 4; ++i)
        #pragma unroll
        for (int j = 0; j < WC; ++j)
            acc[i][j] = (f32x4){0.f, 0.f, 0.f, 0.f};

    for (int k0 = 0; k0 < K; k0 += 32) {
        if (k0) __syncthreads();
        // --- stage A: 128 rows x 32 k, float4 global loads, split to hi/lo ---
        #pragma unroll
        for (int it = 0; it < 4; ++it) {
            int l   = tid + it * 256;     // 0..1023
            int row = l >> 3;
            int k4  = l & 7;
            int gr  = bm + row;
            float4 v = make_float4(0.f, 0.f, 0.f, 0.f);
            if (gr < M) v = *(const float4*)&A[(size_t)gr * K + k0 + k4 * 4];
            float vv[4] = {v.x, v.y, v.z, v.w};
            short h[4], lo[4];
            #pragma unroll
            for (int j = 0; j < 4; ++j) {
                h[j]  = f2bf(vv[j]);
                lo[j] = f2bf(vv[j] - bf2f(h[j]));
            }
            *(short4*)&Ahi[row][k4 * 4] = make_short4(h[0], h[1], h[2], h[3]);
            *(short4*)&Alo[row][k4 * 4] = make_short4(lo[0], lo[1], lo[2], lo[3]);
        }
        // --- stage W transposed: Wt[col][k], scalar loads (coalesced in wc_) ---
        #pragma unroll
        for (int kk = 0; kk < KC; kk += 4) {
            short h[4], lo[4];
            #pragma unroll
            for (int j = 0; j < 4; ++j) {
                float w = W[(size_t)(k0 + kg * KC + kk + j) * F + bn + wc_];
                h[j]  = f2bf(w);
                lo[j] = f2bf(w - bf2f(h[j]));
            }
            *(short4*)&Whi[wc_][kg * KC + kk] = make_short4(h[0], h[1], h[2], h[3]);
            *(short4*)&Wlo[wc_][kg * KC + kk] = make_short4(lo[0], lo[1], lo[2], lo[3]);
        }
        __syncthreads();
        // --- fragments + MFMA ---
        bf16x8 ah[4], al[4], wh[WC], wl[WC];
        #pragma unroll
        for (int ar = 0; ar < 4; ++ar) {
            ah[ar] = *(const bf16x8*)&Ahi[wy * 64 + ar * 16 + frow][fk];
            al[ar] = *(const bf16x8*)&Alo[wy * 64 + ar * 16 + frow][fk];
        }
        #pragma unroll
        for (int wc = 0; wc < WC; ++wc) {
            wh[wc] = *(const bf16x8*)&Whi[wx * (BN / 2) + wc * 16 + frow][fk];
            wl[wc] = *(const bf16x8*)&Wlo[wx * (BN / 2) + wc * 16 + frow][fk];
        }
        #pragma unroll
        for (int ar = 0; ar < 4; ++ar)
            #pragma unroll
            for (int wc = 0; wc < WC; ++wc) {
                acc[ar][wc] = __builtin_amdgcn_mfma_f32_16x16x32_bf16(ah[ar], wh[wc], acc[ar][wc], 0, 0, 0);
                acc[ar][wc] = __builtin_amdgcn_mfma_f32_16x16x32_bf16(ah[ar], wl[wc], acc[ar][wc], 0, 0, 0);
                acc[ar][wc] = __builtin_amdgcn_mfma_f32_16x16x32_bf16(al[ar], wh[wc], acc[ar][wc], 0, 0, 0);
            }
    }
    // --- store P; C/D layout: col=lane&15, row=(lane>>4)*4+reg (m89) ---
    #pragma unroll
    for (int ar = 0; ar < 4; ++ar)
        #pragma unroll
        for (int r = 0; r < 4; ++r) {
            int row = bm + wy * 64 + ar * 16 + (lane >> 4) * 4 + r;
            if (row >= M) continue;
            #pragma unroll
            for (int wc = 0; wc < WC; ++wc) {
                int col = bn + wx * (BN / 2) + wc * 16 + (lane & 15);
                storeP(&P[(size_t)row * F + col], acc[ar][wc][r]);
            }
        }
}

// ---------------------------------------------------------------------------
// Aggregation: out[c] = sn*P[c] + sum_e norm_e * P[row_e] + b
// One wave per node, lane-vectorized (F = VEC*64); 4-edge unroll for MLP.
// fp32 accumulate/output. PT = __half or float.
// ---------------------------------------------------------------------------

template <int VEC>
__device__ __forceinline__ void pload(float* d, const __half* s) {
    if constexpr (VEC == 4) {
        union { short4 s4; __half h[4]; } u;
        u.s4 = *(const short4*)s;
        #pragma unroll
        for (int j = 0; j < 4; ++j) d[j] = __half2float(u.h[j]);
    } else if constexpr (VEC == 2) {
        union { short2 s2; __half h[2]; } u;
        u.s2 = *(const short2*)s;
        d[0] = __half2float(u.h[0]); d[1] = __half2float(u.h[1]);
    } else {
        d[0] = __half2float(*s);
    }
}
template <int VEC>
__device__ __forceinline__ void pload(float* d, const float* s) {
    if constexpr (VEC == 4) { float4 v = *(const float4*)s; d[0]=v.x; d[1]=v.y; d[2]=v.z; d[3]=v.w; }
    else if constexpr (VEC == 2) { float2 v = *(const float2*)s; d[0]=v.x; d[1]=v.y; }
    else { d[0] = *s; }
}
template <int VEC>
__device__ __forceinline__ void fstore(float* d, const float* s) {
    if constexpr (VEC == 4) { *(float4*)d = make_float4(s[0], s[1], s[2], s[3]); }
    else if constexpr (VEC == 2) { *(float2*)d = make_float2(s[0], s[1]); }
    else { *d = s[0]; }
}

template <int VEC, bool RELU, typename PT>
__global__ __launch_bounds__(256) void agg_kernel(
    const PT* __restrict__ pre, const float* __restrict__ bias,
    const int* __restrict__ offsets, const int* __restrict__ csr_row,
    const float* __restrict__ csr_norm, const float* __restrict__ dinv,
    float* __restrict__ out, int n) {
    constexpr int F = VEC * 64;
    const int wave = threadIdx.x >> 6;
    const int lane = threadIdx.x & 63;
    const int c = blockIdx.x * 4 + wave;
    if (c >= n) return;
    const float di = dinv[c];
    const float sn = di * di;
    float acc[VEC], t0[VEC], t1[VEC], t2[VEC], t3[VEC], bv[VEC];
    pload<VEC>(acc, pre + (size_t)c * F + lane * VEC);
    #pragma unroll
    for (int v = 0; v < VEC; ++v) acc[v] *= sn;
    const int beg = offsets[c], end = offsets[c + 1];
    int j = beg;
    for (; j + 3 < end; j += 4) {
        int   r0 = csr_row[j],      r1 = csr_row[j + 1];
        int   r2 = csr_row[j + 2],  r3 = csr_row[j + 3];
        float w0 = csr_norm[j],     w1 = csr_norm[j + 1];
        float w2 = csr_norm[j + 2], w3 = csr_norm[j + 3];
        pload<VEC>(t0, pre + (size_t)r0 * F + lane * VEC);
        pload<VEC>(t1, pre + (size_t)r1 * F + lane * VEC);
        pload<VEC>(t2, pre + (size_t)r2 * F + lane * VEC);
        pload<VEC>(t3, pre + (size_t)r3 * F + lane * VEC);
        #pragma unroll
        for (int v = 0; v < VEC; ++v) acc[v] = fmaf(w0, t0[v], acc[v]);
        #pragma unroll
        for (int v = 0; v < VEC; ++v) acc[v] = fmaf(w1, t1[v], acc[v]);
        #pragma unroll
        for (int v = 0; v < VEC; ++v) acc[v] = fmaf(w2, t2[v], acc[v]);
        #pragma unroll
        for (int v = 0; v < VEC; ++v) acc[v] = fmaf(w3, t3[v], acc[v]);
    }
    for (; j < end; ++j) {
        int r0 = csr_row[j]; float w0 = csr_norm[j];
        pload<VEC>(t0, pre + (size_t)r0 * F + lane * VEC);
        #pragma unroll
        for (int v = 0; v < VEC; ++v) acc[v] = fmaf(w0, t0[v], acc[v]);
    }
    pload<VEC>(bv, bias + lane * VEC);
    #pragma unroll
    for (int v = 0; v < VEC; ++v) {
        float o = acc[v] + bv[v];
        if (RELU) o = fmaxf(o, 0.f);
        acc[v] = o;
    }
    fstore<VEC>(out + (size_t)c * F + lane * VEC, acc);
}

// ---------------------------------------------------------------------------

extern "C" void kernel_launch(void* const* d_in, const int* in_sizes, int n_in,
                              void* d_out, int out_size, void* d_ws, size_t ws_size,
                              hipStream_t stream) {
    const float* x  = (const float*)d_in[0];
    const int*   ei = (const int*)  d_in[1];   // [2,E] int32
    const float* ew = (const float*)d_in[2];
    const float* W1 = (const float*)d_in[3];
    const float* b1 = (const float*)d_in[4];
    const float* W2 = (const float*)d_in[5];
    const float* b2 = (const float*)d_in[6];
    const float* W3 = (const float*)d_in[7];
    const float* b3 = (const float*)d_in[8];
    const float* W4 = (const float*)d_in[9];
    const float* b4 = (const float*)d_in[10];

    const int N = in_sizes[0] / IN_DIM;
    const int E = in_sizes[2];

    char* p = (char*)d_ws;
    auto alloc = [&](size_t bytes) -> void* {
        void* r = (void*)p;
        p += (bytes + 255) & ~(size_t)255;
        return r;
    };
    float*  deg      = (float*)alloc((size_t)N * 4);
    float*  dinv     = (float*)alloc((size_t)N * 4);
    int*    counts   = (int*)  alloc((size_t)N * 4);
    int*    offsets  = (int*)  alloc((size_t)(N + 1) * 4);
    int*    fillpos  = (int*)  alloc((size_t)N * 4);
    int*    bsum     = (int*)  alloc((size_t)64 * 4);
    int*    csr_row  = (int*)  alloc((size_t)E * 4);
    float*  csr_norm = (float*)alloc((size_t)E * 4);
    __half* bufP     = (__half*)alloc((size_t)N * HID * 2);  // GEMM out (f16, width<=256)
    float*  bufH     = (float*) alloc((size_t)N * HID * 4);  // agg out (fp32, width 256)
    float*  bufZ     = (float*) alloc((size_t)N * LAT * 4);  // latent (fp32, width 64)
    // layer-4 fp32 P aliases bufP exactly: N*256*2 bytes == N*128*4 bytes
    float*  bufP32   = (float*)bufP;

    const int gN  = (N + 255) / 256;
    const int gE  = (E + 255) / 256;
    const int nbS = (N + 1023) / 1024;   // scan blocks (49 for N=50000; must be <=64)
    const int nbM = (N + 127) / 128;
    const int nodeBlocks = (N + 3) / 4;

    // --- normalization + CSR build ---
    k_init      <<<gN, 256, 0, stream>>>(deg, counts, N);
    k_edge_deg  <<<gE, 256, 0, stream>>>(ei, ew, deg, counts, E);
    k_dinv      <<<gN, 256, 0, stream>>>(deg, dinv, N);
    k_blocksum  <<<nbS, 1024, 0, stream>>>(counts, bsum, N);
    k_scan_bsums<<<1, 64, 0, stream>>>(bsum, nbS, offsets, N);
    k_scan_apply<<<nbS, 1024, 0, stream>>>(counts, bsum, offsets, fillpos, N);
    k_fill      <<<gE, 256, 0, stream>>>(ei, ew, dinv, fillpos, csr_row, csr_norm, E);

    // --- layer 1: x @ W1 -> agg+b1+relu ---
    gemm_mfma<128, __half><<<dim3(nbM, HID / 128), 256, 0, stream>>>(x, W1, bufP, N, IN_DIM, HID);
    agg_kernel<4, true, __half><<<nodeBlocks, 256, 0, stream>>>(bufP, b1, offsets, csr_row, csr_norm, dinv, bufH, N);

    // --- layer 2: h1 @ W2 -> agg+b2 (latent) ---
    gemm_mfma<64, __half><<<dim3(nbM, LAT / 64), 256, 0, stream>>>(bufH, W2, bufP, N, HID, LAT);
    agg_kernel<1, false, __half><<<nodeBlocks, 256, 0, stream>>>(bufP, b2, offsets, csr_row, csr_norm, dinv, bufZ, N);

    // --- layer 3: z @ W3 -> agg+b3+relu ---
    gemm_mfma<128, __half><<<dim3(nbM, HID / 128), 256, 0, stream>>>(bufZ, W3, bufP, N, LAT, HID);
    agg_kernel<4, true, __half><<<nodeBlocks, 256, 0, stream>>>(bufP, b3, offsets, csr_row, csr_norm, dinv, bufH, N);

    // --- layer 4: h3 @ W4 -> agg+b4 -> d_out (fp32 P: high-sn nodes see fp32 error) ---
    gemm_mfma<128, float><<<dim3(nbM, IN_DIM / 128), 256, 0, stream>>>(bufH, W4, bufP32, N, HID, IN_DIM);
    agg_kernel<2, false, float><<<nodeBlocks, 256, 0, stream>>>(bufP32, b4, offsets, csr_row, csr_norm, dinv, (float*)d_out, N);
}

// Round 6
// 480.905 us; speedup vs baseline: 1.7681x; 1.1362x over previous
//
#include <hip/hip_runtime.h>
#include <hip/hip_fp16.h>

#define IN_DIM 128
#define HID    256
#define LAT    64

typedef __attribute__((ext_vector_type(8))) short bf16x8;
typedef __attribute__((ext_vector_type(4))) float f32x4;

// ---------------------------------------------------------------------------
// bf16 split helpers (round-to-nearest-even)
// ---------------------------------------------------------------------------
__device__ __forceinline__ short f2bf(float f) {
    union { float f; unsigned u; } v; v.f = f;
    unsigned r = v.u + 0x7fffu + ((v.u >> 16) & 1u);
    return (short)(r >> 16);
}
__device__ __forceinline__ float bf2f(short s) {
    union { unsigned u; float f; } v; v.u = ((unsigned)(unsigned short)s) << 16;
    return v.f;
}

__device__ __forceinline__ void storeP(__half* p, float v) { *p = __float2half(v); }
__device__ __forceinline__ void storeP(float*  p, float v) { *p = v; }

// ---------------------------------------------------------------------------
// Preprocessing: GCN symmetric normalization + CSR-by-destination.
// Single packed u64 atomic per edge: bits [40,64) = edge count, bits [0,40) =
// Q20 fixed-point weight sum (self-loop weight 1.0 pre-seeded by k_init).
// Returned old value gives the edge's rank within its destination -> CSR fill
// needs no atomic.
// ---------------------------------------------------------------------------

#define FIXSCALE 1048576.0f   // 2^20

__global__ void k_init(unsigned long long* __restrict__ packed, int n) {
    int i = blockIdx.x * 256 + threadIdx.x;
    if (i < n) packed[i] = (unsigned long long)(1u << 20);   // self-loop, count 0
}

__global__ void k_edge_acc(const int* __restrict__ ei, const float* __restrict__ ew,
                           unsigned long long* __restrict__ packed,
                           int* __restrict__ rank, int E) {
    int e = blockIdx.x * 256 + threadIdx.x;
    if (e < E) {
        int c = ei[E + e];
        unsigned fx = (unsigned)lrintf(ew[e] * FIXSCALE);
        unsigned long long old =
            atomicAdd(&packed[c], ((unsigned long long)1 << 40) | (unsigned long long)fx);
        rank[e] = (int)(old >> 40);
    }
}

__global__ void k_derive(const unsigned long long* __restrict__ packed,
                         float* __restrict__ dinv, int* __restrict__ counts, int n) {
    int i = blockIdx.x * 256 + threadIdx.x;
    if (i < n) {
        unsigned long long p = packed[i];
        float deg = (float)(p & (((unsigned long long)1 << 40) - 1)) * (1.0f / FIXSCALE);
        dinv[i]   = rsqrtf(deg);           // deg >= 1 (self loop)
        counts[i] = (int)(p >> 40);
    }
}

// --- coalesced 3-phase exclusive scan (n <= 64*1024) ---
__global__ __launch_bounds__(1024) void k_blocksum(const int* __restrict__ counts,
                                                   int* __restrict__ bsum, int n) {
    __shared__ int ws[16];
    const int t = threadIdx.x, lane = t & 63, wv = t >> 6;
    int i = blockIdx.x * 1024 + t;
    int v = (i < n) ? counts[i] : 0;
    #pragma unroll
    for (int d = 1; d < 64; d <<= 1) v += __shfl_xor(v, d);
    if (lane == 0) ws[wv] = v;
    __syncthreads();
    if (wv == 0 && lane < 16) {
        int x = ws[lane];
        #pragma unroll
        for (int d = 1; d < 16; d <<= 1) x += __shfl_xor(x, d, 16);
        if (lane == 0) bsum[blockIdx.x] = x;
    }
}

__global__ void k_scan_bsums(int* __restrict__ bsum, int nb,
                             int* __restrict__ offsets, int n) {
    int lane = threadIdx.x;          // 64 threads
    int v = (lane < nb) ? bsum[lane] : 0;
    #pragma unroll
    for (int d = 1; d < 64; d <<= 1) {
        int u = __shfl_up(v, d);
        if (lane >= d) v += u;
    }
    if (lane < nb) bsum[lane] = v;   // inclusive
    if (lane == nb - 1) offsets[n] = v;
}

__global__ __launch_bounds__(1024) void k_scan_apply(const int* __restrict__ counts,
                                                     const int* __restrict__ bsum,
                                                     int* __restrict__ offsets, int n) {
    __shared__ int ws[16];
    const int t = threadIdx.x, lane = t & 63, wv = t >> 6;
    int i = blockIdx.x * 1024 + t;
    int v = (i < n) ? counts[i] : 0;
    int s = v;
    #pragma unroll
    for (int d = 1; d < 64; d <<= 1) {
        int u = __shfl_up(s, d);
        if (lane >= d) s += u;
    }
    if (lane == 63) ws[wv] = s;
    __syncthreads();
    if (wv == 0 && lane < 16) {
        int x = ws[lane];
        #pragma unroll
        for (int d = 1; d < 16; d <<= 1) {
            int u = __shfl_up(x, d, 16);
            if (lane >= d) x += u;
        }
        ws[lane] = x;
    }
    __syncthreads();
    int base = (blockIdx.x ? bsum[blockIdx.x - 1] : 0) + (wv ? ws[wv - 1] : 0);
    if (i < n) offsets[i] = base + s - v;
}

// atomic-free CSR fill: pos = offsets[col] + rank[e]
__global__ void k_fill(const int* __restrict__ ei, const float* __restrict__ ew,
                       const float* __restrict__ dinv, const int* __restrict__ offsets,
                       const int* __restrict__ rank,
                       int* __restrict__ csr_row, float* __restrict__ csr_norm, int E) {
    int e = blockIdx.x * 256 + threadIdx.x;
    if (e < E) {
        int r = ei[e];
        int c = ei[E + e];
        int pos = offsets[c] + rank[e];
        csr_row[pos]  = r;
        csr_norm[pos] = dinv[r] * ew[e] * dinv[c];
    }
}

// ---------------------------------------------------------------------------
// MFMA GEMM with bf16 Markidis split: P[M,F] = A_f32[M,K] @ W_f32[K,F].
// BM=128, BK=32, BN template (64 or 128). 256 threads = 4 waves in 2x2 grid.
// LDS tiles row-pitch 40 bf16 (80B): fragment reads are <=2-way (free, m136).
// 3 MFMAs per fragment pair: hi*hi + hi*lo + lo*hi (error ~2^-16 relative).
// K % 32 == 0 required. PT = __half (inner layers) or float (output layer).
// ---------------------------------------------------------------------------
template <int BN, typename PT>
__global__ __launch_bounds__(256) void gemm_mfma(const float* __restrict__ A,
                                                 const float* __restrict__ W,
                                                 PT* __restrict__ P,
                                                 int M, int K, int F) {
    constexpr int WC = BN / 32;          // col fragments per wave
    __shared__ alignas(16) short Ahi[128][40];
    __shared__ alignas(16) short Alo[128][40];
    __shared__ alignas(16) short Whi[BN][40];
    __shared__ alignas(16) short Wlo[BN][40];

    const int bm  = blockIdx.x * 128;
    const int bn  = blockIdx.y * BN;
    const int tid = threadIdx.x;
    const int wv  = tid >> 6;
    const int wy  = wv >> 1;             // 0..1 : row half
    const int wx  = wv & 1;              // 0..1 : col half
    const int lane = tid & 63;
    const int frow = lane & 15;          // fragment row (A) / col (B)
    const int fk   = (lane >> 4) * 8;    // fragment k offset (elements)

    const int wc_ = tid % BN;            // column within tile
    const int kg  = tid / BN;            // k group
    constexpr int KC = 32 * BN / 256;    // k elems per thread (16 or 8)

    f32x4 acc[4][WC];
    #pragma unroll
    for (int i = 0; i < 4; ++i)
        #pragma unroll
        for (int j = 0; j < WC; ++j)
            acc[i][j] = (f32x4){0.f, 0.f, 0.f, 0.f};

    for (int k0 = 0; k0 < K; k0 += 32) {
        if (k0) __syncthreads();
        // --- stage A: 128 rows x 32 k, float4 global loads, split to hi/lo ---
        #pragma unroll
        for (int it = 0; it < 4; ++it) {
            int l   = tid + it * 256;     // 0..1023
            int row = l >> 3;
            int k4  = l & 7;
            int gr  = bm + row;
            float4 v = make_float4(0.f, 0.f, 0.f, 0.f);
            if (gr < M) v = *(const float4*)&A[(size_t)gr * K + k0 + k4 * 4];
            float vv[4] = {v.x, v.y, v.z, v.w};
            short h[4], lo[4];
            #pragma unroll
            for (int j = 0; j < 4; ++j) {
                h[j]  = f2bf(vv[j]);
                lo[j] = f2bf(vv[j] - bf2f(h[j]));
            }
            *(short4*)&Ahi[row][k4 * 4] = make_short4(h[0], h[1], h[2], h[3]);
            *(short4*)&Alo[row][k4 * 4] = make_short4(lo[0], lo[1], lo[2], lo[3]);
        }
        // --- stage W transposed: Wt[col][k], scalar loads (coalesced in wc_) ---
        #pragma unroll
        for (int kk = 0; kk < KC; kk += 4) {
            short h[4], lo[4];
            #pragma unroll
            for (int j = 0; j < 4; ++j) {
                float w = W[(size_t)(k0 + kg * KC + kk + j) * F + bn + wc_];
                h[j]  = f2bf(w);
                lo[j] = f2bf(w - bf2f(h[j]));
            }
            *(short4*)&Whi[wc_][kg * KC + kk] = make_short4(h[0], h[1], h[2], h[3]);
            *(short4*)&Wlo[wc_][kg * KC + kk] = make_short4(lo[0], lo[1], lo[2], lo[3]);
        }
        __syncthreads();
        // --- fragments + MFMA ---
        bf16x8 ah[4], al[4], wh[WC], wl[WC];
        #pragma unroll
        for (int ar = 0; ar < 4; ++ar) {
            ah[ar] = *(const bf16x8*)&Ahi[wy * 64 + ar * 16 + frow][fk];
            al[ar] = *(const bf16x8*)&Alo[wy * 64 + ar * 16 + frow][fk];
        }
        #pragma unroll
        for (int wc = 0; wc < WC; ++wc) {
            wh[wc] = *(const bf16x8*)&Whi[wx * (BN / 2) + wc * 16 + frow][fk];
            wl[wc] = *(const bf16x8*)&Wlo[wx * (BN / 2) + wc * 16 + frow][fk];
        }
        #pragma unroll
        for (int ar = 0; ar < 4; ++ar)
            #pragma unroll
            for (int wc = 0; wc < WC; ++wc) {
                acc[ar][wc] = __builtin_amdgcn_mfma_f32_16x16x32_bf16(ah[ar], wh[wc], acc[ar][wc], 0, 0, 0);
                acc[ar][wc] = __builtin_amdgcn_mfma_f32_16x16x32_bf16(ah[ar], wl[wc], acc[ar][wc], 0, 0, 0);
                acc[ar][wc] = __builtin_amdgcn_mfma_f32_16x16x32_bf16(al[ar], wh[wc], acc[ar][wc], 0, 0, 0);
            }
    }
    // --- store P; C/D layout: col=lane&15, row=(lane>>4)*4+reg (m89) ---
    #pragma unroll
    for (int ar = 0; ar < 4; ++ar)
        #pragma unroll
        for (int r = 0; r < 4; ++r) {
            int row = bm + wy * 64 + ar * 16 + (lane >> 4) * 4 + r;
            if (row >= M) continue;
            #pragma unroll
            for (int wc = 0; wc < WC; ++wc) {
                int col = bn + wx * (BN / 2) + wc * 16 + (lane & 15);
                storeP(&P[(size_t)row * F + col], acc[ar][wc][r]);
            }
        }
}

// ---------------------------------------------------------------------------
// Aggregation: out[c] = sn*P[c] + sum_e norm_e * P[row_e] + b
// One wave per node, lane-vectorized (F = VEC*64); 4-edge unroll for MLP.
// fp32 accumulate/output. PT = __half or float.
// ---------------------------------------------------------------------------

template <int VEC>
__device__ __forceinline__ void pload(float* d, const __half* s) {
    if constexpr (VEC == 4) {
        union { short4 s4; __half h[4]; } u;
        u.s4 = *(const short4*)s;
        #pragma unroll
        for (int j = 0; j < 4; ++j) d[j] = __half2float(u.h[j]);
    } else if constexpr (VEC == 2) {
        union { short2 s2; __half h[2]; } u;
        u.s2 = *(const short2*)s;
        d[0] = __half2float(u.h[0]); d[1] = __half2float(u.h[1]);
    } else {
        d[0] = __half2float(*s);
    }
}
template <int VEC>
__device__ __forceinline__ void pload(float* d, const float* s) {
    if constexpr (VEC == 4) { float4 v = *(const float4*)s; d[0]=v.x; d[1]=v.y; d[2]=v.z; d[3]=v.w; }
    else if constexpr (VEC == 2) { float2 v = *(const float2*)s; d[0]=v.x; d[1]=v.y; }
    else { d[0] = *s; }
}
template <int VEC>
__device__ __forceinline__ void fstore(float* d, const float* s) {
    if constexpr (VEC == 4) { *(float4*)d = make_float4(s[0], s[1], s[2], s[3]); }
    else if constexpr (VEC == 2) { *(float2*)d = make_float2(s[0], s[1]); }
    else { *d = s[0]; }
}

template <int VEC, bool RELU, typename PT>
__global__ __launch_bounds__(256) void agg_kernel(
    const PT* __restrict__ pre, const float* __restrict__ bias,
    const int* __restrict__ offsets, const int* __restrict__ csr_row,
    const float* __restrict__ csr_norm, const float* __restrict__ dinv,
    float* __restrict__ out, int n) {
    constexpr int F = VEC * 64;
    const int wave = threadIdx.x >> 6;
    const int lane = threadIdx.x & 63;
    const int c = blockIdx.x * 4 + wave;
    if (c >= n) return;
    const float di = dinv[c];
    const float sn = di * di;
    float acc[VEC], t0[VEC], t1[VEC], t2[VEC], t3[VEC], bv[VEC];
    pload<VEC>(acc, pre + (size_t)c * F + lane * VEC);
    #pragma unroll
    for (int v = 0; v < VEC; ++v) acc[v] *= sn;
    const int beg = offsets[c], end = offsets[c + 1];
    int j = beg;
    for (; j + 3 < end; j += 4) {
        int   r0 = csr_row[j],      r1 = csr_row[j + 1];
        int   r2 = csr_row[j + 2],  r3 = csr_row[j + 3];
        float w0 = csr_norm[j],     w1 = csr_norm[j + 1];
        float w2 = csr_norm[j + 2], w3 = csr_norm[j + 3];
        pload<VEC>(t0, pre + (size_t)r0 * F + lane * VEC);
        pload<VEC>(t1, pre + (size_t)r1 * F + lane * VEC);
        pload<VEC>(t2, pre + (size_t)r2 * F + lane * VEC);
        pload<VEC>(t3, pre + (size_t)r3 * F + lane * VEC);
        #pragma unroll
        for (int v = 0; v < VEC; ++v) acc[v] = fmaf(w0, t0[v], acc[v]);
        #pragma unroll
        for (int v = 0; v < VEC; ++v) acc[v] = fmaf(w1, t1[v], acc[v]);
        #pragma unroll
        for (int v = 0; v < VEC; ++v) acc[v] = fmaf(w2, t2[v], acc[v]);
        #pragma unroll
        for (int v = 0; v < VEC; ++v) acc[v] = fmaf(w3, t3[v], acc[v]);
    }
    for (; j < end; ++j) {
        int r0 = csr_row[j]; float w0 = csr_norm[j];
        pload<VEC>(t0, pre + (size_t)r0 * F + lane * VEC);
        #pragma unroll
        for (int v = 0; v < VEC; ++v) acc[v] = fmaf(w0, t0[v], acc[v]);
    }
    pload<VEC>(bv, bias + lane * VEC);
    #pragma unroll
    for (int v = 0; v < VEC; ++v) {
        float o = acc[v] + bv[v];
        if (RELU) o = fmaxf(o, 0.f);
        acc[v] = o;
    }
    fstore<VEC>(out + (size_t)c * F + lane * VEC, acc);
}

// ---------------------------------------------------------------------------

extern "C" void kernel_launch(void* const* d_in, const int* in_sizes, int n_in,
                              void* d_out, int out_size, void* d_ws, size_t ws_size,
                              hipStream_t stream) {
    const float* x  = (const float*)d_in[0];
    const int*   ei = (const int*)  d_in[1];   // [2,E] int32
    const float* ew = (const float*)d_in[2];
    const float* W1 = (const float*)d_in[3];
    const float* b1 = (const float*)d_in[4];
    const float* W2 = (const float*)d_in[5];
    const float* b2 = (const float*)d_in[6];
    const float* W3 = (const float*)d_in[7];
    const float* b3 = (const float*)d_in[8];
    const float* W4 = (const float*)d_in[9];
    const float* b4 = (const float*)d_in[10];

    const int N = in_sizes[0] / IN_DIM;
    const int E = in_sizes[2];

    char* p = (char*)d_ws;
    auto alloc = [&](size_t bytes) -> void* {
        void* r = (void*)p;
        p += (bytes + 255) & ~(size_t)255;
        return r;
    };
    unsigned long long* packed = (unsigned long long*)alloc((size_t)N * 8);
    float*  dinv     = (float*)alloc((size_t)N * 4);
    int*    counts   = (int*)  alloc((size_t)N * 4);
    int*    offsets  = (int*)  alloc((size_t)(N + 1) * 4);
    int*    bsum     = (int*)  alloc((size_t)64 * 4);
    int*    rank     = (int*)  alloc((size_t)E * 4);
    int*    csr_row  = (int*)  alloc((size_t)E * 4);
    float*  csr_norm = (float*)alloc((size_t)E * 4);
    __half* bufP     = (__half*)alloc((size_t)N * HID * 2);  // GEMM out (f16, width<=256)
    float*  bufH     = (float*) alloc((size_t)N * HID * 4);  // agg out (fp32, width 256)
    float*  bufZ     = (float*) alloc((size_t)N * LAT * 4);  // latent (fp32, width 64)
    // layer-4 fp32 P aliases bufP exactly: N*256*2 bytes == N*128*4 bytes
    float*  bufP32   = (float*)bufP;

    const int gN  = (N + 255) / 256;
    const int gE  = (E + 255) / 256;
    const int nbS = (N + 1023) / 1024;   // scan blocks (49 for N=50000; must be <=64)
    const int nbM = (N + 127) / 128;
    const int nodeBlocks = (N + 3) / 4;

    // --- normalization + CSR build (1 atomic per edge total) ---
    k_init      <<<gN, 256, 0, stream>>>(packed, N);
    k_edge_acc  <<<gE, 256, 0, stream>>>(ei, ew, packed, rank, E);
    k_derive    <<<gN, 256, 0, stream>>>(packed, dinv, counts, N);
    k_blocksum  <<<nbS, 1024, 0, stream>>>(counts, bsum, N);
    k_scan_bsums<<<1, 64, 0, stream>>>(bsum, nbS, offsets, N);
    k_scan_apply<<<nbS, 1024, 0, stream>>>(counts, bsum, offsets, N);
    k_fill      <<<gE, 256, 0, stream>>>(ei, ew, dinv, offsets, rank, csr_row, csr_norm, E);

    // --- layer 1: x @ W1 -> agg+b1+relu ---
    gemm_mfma<128, __half><<<dim3(nbM, HID / 128), 256, 0, stream>>>(x, W1, bufP, N, IN_DIM, HID);
    agg_kernel<4, true, __half><<<nodeBlocks, 256, 0, stream>>>(bufP, b1, offsets, csr_row, csr_norm, dinv, bufH, N);

    // --- layer 2: h1 @ W2 -> agg+b2 (latent) ---
    gemm_mfma<64, __half><<<dim3(nbM, LAT / 64), 256, 0, stream>>>(bufH, W2, bufP, N, HID, LAT);
    agg_kernel<1, false, __half><<<nodeBlocks, 256, 0, stream>>>(bufP, b2, offsets, csr_row, csr_norm, dinv, bufZ, N);

    // --- layer 3: z @ W3 -> agg+b3+relu ---
    gemm_mfma<128, __half><<<dim3(nbM, HID / 128), 256, 0, stream>>>(bufZ, W3, bufP, N, LAT, HID);
    agg_kernel<4, true, __half><<<nodeBlocks, 256, 0, stream>>>(bufP, b3, offsets, csr_row, csr_norm, dinv, bufH, N);

    // --- layer 4: h3 @ W4 -> agg+b4 -> d_out (fp32 P: high-sn nodes see fp32 error) ---
    gemm_mfma<128, float><<<dim3(nbM, IN_DIM / 128), 256, 0, stream>>>(bufH, W4, bufP32, N, HID, IN_DIM);
    agg_kernel<2, false, float><<<nodeBlocks, 256, 0, stream>>>(bufP32, b4, offsets, csr_row, csr_norm, dinv, (float*)d_out, N);
}

// Round 10
// 441.038 us; speedup vs baseline: 1.9279x; 1.0904x over previous
//
#include <hip/hip_runtime.h>
#include <hip/hip_fp16.h>

#define IN_DIM 128
#define HID    256
#define LAT    64

typedef __attribute__((ext_vector_type(8))) short bf16x8;
typedef __attribute__((ext_vector_type(4))) float f32x4;

// ---------------------------------------------------------------------------
// bf16 split helpers (round-to-nearest-even)
// ---------------------------------------------------------------------------
__device__ __forceinline__ short f2bf(float f) {
    union { float f; unsigned u; } v; v.f = f;
    unsigned r = v.u + 0x7fffu + ((v.u >> 16) & 1u);
    return (short)(r >> 16);
}
__device__ __forceinline__ float bf2f(short s) {
    union { unsigned u; float f; } v; v.u = ((unsigned)(unsigned short)s) << 16;
    return v.f;
}

__device__ __forceinline__ void storeP(__half* p, float v) { *p = __float2half(v); }
__device__ __forceinline__ void storeP(float*  p, float v) { *p = v; }

// ---------------------------------------------------------------------------
// Preprocessing: packed u64 atomic (count | Q20 weight-sum) -> rank; CSR fill
// without atomics. CSR entries are int2 {row, norm-bits}.
// ---------------------------------------------------------------------------

#define FIXSCALE 1048576.0f   // 2^20

__global__ void k_init(unsigned long long* __restrict__ packed, int n) {
    int i = blockIdx.x * 256 + threadIdx.x;
    if (i < n) packed[i] = (unsigned long long)(1u << 20);   // self-loop, count 0
}

__global__ void k_edge_acc(const int* __restrict__ ei, const float* __restrict__ ew,
                           unsigned long long* __restrict__ packed,
                           int* __restrict__ rank, int E) {
    int e = blockIdx.x * 256 + threadIdx.x;
    if (e < E) {
        int c = ei[E + e];
        unsigned fx = (unsigned)lrintf(ew[e] * FIXSCALE);
        unsigned long long old =
            atomicAdd(&packed[c], ((unsigned long long)1 << 40) | (unsigned long long)fx);
        rank[e] = (int)(old >> 40);
    }
}

__global__ void k_derive(const unsigned long long* __restrict__ packed,
                         float* __restrict__ dinv, int* __restrict__ counts, int n) {
    int i = blockIdx.x * 256 + threadIdx.x;
    if (i < n) {
        unsigned long long p = packed[i];
        float deg = (float)(p & (((unsigned long long)1 << 40) - 1)) * (1.0f / FIXSCALE);
        dinv[i]   = rsqrtf(deg);           // deg >= 1 (self loop)
        counts[i] = (int)(p >> 40);
    }
}

// --- coalesced 3-phase exclusive scan (n <= 64*1024) ---
__global__ __launch_bounds__(1024) void k_blocksum(const int* __restrict__ counts,
                                                   int* __restrict__ bsum, int n) {
    __shared__ int ws[16];
    const int t = threadIdx.x, lane = t & 63, wv = t >> 6;
    int i = blockIdx.x * 1024 + t;
    int v = (i < n) ? counts[i] : 0;
    #pragma unroll
    for (int d = 1; d < 64; d <<= 1) v += __shfl_xor(v, d);
    if (lane == 0) ws[wv] = v;
    __syncthreads();
    if (wv == 0 && lane < 16) {
        int x = ws[lane];
        #pragma unroll
        for (int d = 1; d < 16; d <<= 1) x += __shfl_xor(x, d, 16);
        if (lane == 0) bsum[blockIdx.x] = x;
    }
}

__global__ void k_scan_bsums(int* __restrict__ bsum, int nb,
                             int* __restrict__ offsets, int n) {
    int lane = threadIdx.x;          // 64 threads
    int v = (lane < nb) ? bsum[lane] : 0;
    #pragma unroll
    for (int d = 1; d < 64; d <<= 1) {
        int u = __shfl_up(v, d);
        if (lane >= d) v += u;
    }
    if (lane < nb) bsum[lane] = v;   // inclusive
    if (lane == nb - 1) offsets[n] = v;
}

__global__ __launch_bounds__(1024) void k_scan_apply(const int* __restrict__ counts,
                                                     const int* __restrict__ bsum,
                                                     int* __restrict__ offsets, int n) {
    __shared__ int ws[16];
    const int t = threadIdx.x, lane = t & 63, wv = t >> 6;
    int i = blockIdx.x * 1024 + t;
    int v = (i < n) ? counts[i] : 0;
    int s = v;
    #pragma unroll
    for (int d = 1; d < 64; d <<= 1) {
        int u = __shfl_up(s, d);
        if (lane >= d) s += u;
    }
    if (lane == 63) ws[wv] = s;
    __syncthreads();
    if (wv == 0 && lane < 16) {
        int x = ws[lane];
        #pragma unroll
        for (int d = 1; d < 16; d <<= 1) {
            int u = __shfl_up(x, d, 16);
            if (lane >= d) x += u;
        }
        ws[lane] = x;
    }
    __syncthreads();
    int base = (blockIdx.x ? bsum[blockIdx.x - 1] : 0) + (wv ? ws[wv - 1] : 0);
    if (i < n) offsets[i] = base + s - v;
}

// atomic-free CSR fill: pos = offsets[col] + rank[e]; int2 {row, norm}
__global__ void k_fill(const int* __restrict__ ei, const float* __restrict__ ew,
                       const float* __restrict__ dinv, const int* __restrict__ offsets,
                       const int* __restrict__ rank,
                       int2* __restrict__ csr, int E) {
    int e = blockIdx.x * 256 + threadIdx.x;
    if (e < E) {
        int r = ei[e];
        int c = ei[E + e];
        int pos = offsets[c] + rank[e];
        float nm = dinv[r] * ew[e] * dinv[c];
        csr[pos] = make_int2(r, __float_as_int(nm));
    }
}

// fp32 -> f16 cast, 8 elems/thread (total % 8 == 0)
__global__ void k_cast(const float* __restrict__ x, __half* __restrict__ xh, int total) {
    int idx = (blockIdx.x * 256 + threadIdx.x) * 8;
    if (idx < total) {
        float4 a = *(const float4*)&x[idx];
        float4 b = *(const float4*)&x[idx + 4];
        short4 s0 = make_short4(__half_as_short(__float2half(a.x)), __half_as_short(__float2half(a.y)),
                                __half_as_short(__float2half(a.z)), __half_as_short(__float2half(a.w)));
        short4 s1 = make_short4(__half_as_short(__float2half(b.x)), __half_as_short(__float2half(b.y)),
                                __half_as_short(__float2half(b.z)), __half_as_short(__float2half(b.w)));
        *(short4*)&xh[idx]     = s0;
        *(short4*)&xh[idx + 4] = s1;
    }
}

// ---------------------------------------------------------------------------
// MFMA GEMM with bf16 Markidis split: P[M,F] = A_f32[M,K] @ W_f32[K,F] (+b,relu).
// BM=128, BK=32, BN template (64 or 128). 256 threads = 4 waves in 2x2 grid.
// EPI=true fuses o = relu(o + bias[col]). K % 32 == 0.
// ---------------------------------------------------------------------------
template <int BN, typename PT, bool EPI>
__global__ __launch_bounds__(256) void gemm_mfma(const float* __restrict__ A,
                                                 const float* __restrict__ W,
                                                 const float* __restrict__ bias,
                                                 PT* __restrict__ P,
                                                 int M, int K, int F) {
    constexpr int WC = BN / 32;          // col fragments per wave
    __shared__ alignas(16) short Ahi[128][40];
    __shared__ alignas(16) short Alo[128][40];
    __shared__ alignas(16) short Whi[BN][40];
    __shared__ alignas(16) short Wlo[BN][40];

    const int bm  = blockIdx.x * 128;
    const int bn  = blockIdx.y * BN;
    const int tid = threadIdx.x;
    const int wv  = tid >> 6;
    const int wy  = wv >> 1;             // 0..1 : row half
    const int wx  = wv & 1;              // 0..1 : col half
    const int lane = tid & 63;
    const int frow = lane & 15;
    const int fk   = (lane >> 4) * 8;

    const int wc_ = tid % BN;
    const int kg  = tid / BN;
    constexpr int KC = 32 * BN / 256;

    f32x4 acc[4][WC];
    #pragma unroll
    for (int i = 0; i < 4; ++i)
        #pragma unroll
        for (int j = 0; j < WC; ++j)
            acc[i][j] = (f32x4){0.f, 0.f, 0.f, 0.f};

    for (int k0 = 0; k0 < K; k0 += 32) {
        if (k0) __syncthreads();
        #pragma unroll
        for (int it = 0; it < 4; ++it) {
            int l   = tid + it * 256;
            int row = l >> 3;
            int k4  = l & 7;
            int gr  = bm + row;
            float4 v = make_float4(0.f, 0.f, 0.f, 0.f);
            if (gr < M) v = *(const float4*)&A[(size_t)gr * K + k0 + k4 * 4];
            float vv[4] = {v.x, v.y, v.z, v.w};
            short h[4], lo[4];
            #pragma unroll
            for (int j = 0; j < 4; ++j) {
                h[j]  = f2bf(vv[j]);
                lo[j] = f2bf(vv[j] - bf2f(h[j]));
            }
            *(short4*)&Ahi[row][k4 * 4] = make_short4(h[0], h[1], h[2], h[3]);
            *(short4*)&Alo[row][k4 * 4] = make_short4(lo[0], lo[1], lo[2], lo[3]);
        }
        #pragma unroll
        for (int kk = 0; kk < KC; kk += 4) {
            short h[4], lo[4];
            #pragma unroll
            for (int j = 0; j < 4; ++j) {
                float w = W[(size_t)(k0 + kg * KC + kk + j) * F + bn + wc_];
                h[j]  = f2bf(w);
                lo[j] = f2bf(w - bf2f(h[j]));
            }
            *(short4*)&Whi[wc_][kg * KC + kk] = make_short4(h[0], h[1], h[2], h[3]);
            *(short4*)&Wlo[wc_][kg * KC + kk] = make_short4(lo[0], lo[1], lo[2], lo[3]);
        }
        __syncthreads();
        bf16x8 ah[4], al[4], wh[WC], wl[WC];
        #pragma unroll
        for (int ar = 0; ar < 4; ++ar) {
            ah[ar] = *(const bf16x8*)&Ahi[wy * 64 + ar * 16 + frow][fk];
            al[ar] = *(const bf16x8*)&Alo[wy * 64 + ar * 16 + frow][fk];
        }
        #pragma unroll
        for (int wc = 0; wc < WC; ++wc) {
            wh[wc] = *(const bf16x8*)&Whi[wx * (BN / 2) + wc * 16 + frow][fk];
            wl[wc] = *(const bf16x8*)&Wlo[wx * (BN / 2) + wc * 16 + frow][fk];
        }
        #pragma unroll
        for (int ar = 0; ar < 4; ++ar)
            #pragma unroll
            for (int wc = 0; wc < WC; ++wc) {
                acc[ar][wc] = __builtin_amdgcn_mfma_f32_16x16x32_bf16(ah[ar], wh[wc], acc[ar][wc], 0, 0, 0);
                acc[ar][wc] = __builtin_amdgcn_mfma_f32_16x16x32_bf16(ah[ar], wl[wc], acc[ar][wc], 0, 0, 0);
                acc[ar][wc] = __builtin_amdgcn_mfma_f32_16x16x32_bf16(al[ar], wh[wc], acc[ar][wc], 0, 0, 0);
            }
    }
    #pragma unroll
    for (int ar = 0; ar < 4; ++ar)
        #pragma unroll
        for (int r = 0; r < 4; ++r) {
            int row = bm + wy * 64 + ar * 16 + (lane >> 4) * 4 + r;
            if (row >= M) continue;
            #pragma unroll
            for (int wc = 0; wc < WC; ++wc) {
                int col = bn + wx * (BN / 2) + wc * 16 + (lane & 15);
                float o = acc[ar][wc][r];
                if (EPI) o = fmaxf(o + bias[col], 0.f);
                storeP(&P[(size_t)row * F + col], o);
            }
        }
}

// ---------------------------------------------------------------------------
// Aggregation: out[c] = sn*pre[c] + sum_e norm_e * pre[row_e] (+ bias)
// One wave per node, lane-vectorized (F = VEC*64); 4-edge unroll.
// fp32 accumulate. TIN/TOUT in {__half, float}.
// ---------------------------------------------------------------------------

template <int VEC>
__device__ __forceinline__ void pload(float* d, const __half* s) {
    if constexpr (VEC == 4) {
        union { short4 s4; __half h[4]; } u;
        u.s4 = *(const short4*)s;
        #pragma unroll
        for (int j = 0; j < 4; ++j) d[j] = __half2float(u.h[j]);
    } else if constexpr (VEC == 2) {
        union { short2 s2; __half h[2]; } u;
        u.s2 = *(const short2*)s;
        d[0] = __half2float(u.h[0]); d[1] = __half2float(u.h[1]);
    } else {
        d[0] = __half2float(*s);
    }
}
template <int VEC>
__device__ __forceinline__ void pload(float* d, const float* s) {
    if constexpr (VEC == 4) { float4 v = *(const float4*)s; d[0]=v.x; d[1]=v.y; d[2]=v.z; d[3]=v.w; }
    else if constexpr (VEC == 2) { float2 v = *(const float2*)s; d[0]=v.x; d[1]=v.y; }
    else { d[0] = *s; }
}
template <int VEC>
__device__ __forceinline__ void pstore(__half* d, const float* s) {
    if constexpr (VEC == 4) {
        *(short4*)d = make_short4(__half_as_short(__float2half(s[0])), __half_as_short(__float2half(s[1])),
                                  __half_as_short(__float2half(s[2])), __half_as_short(__float2half(s[3])));
    } else if constexpr (VEC == 2) {
        *(short2*)d = make_short2(__half_as_short(__float2half(s[0])), __half_as_short(__float2half(s[1])));
    } else {
        *d = __float2half(s[0]);
    }
}
template <int VEC>
__device__ __forceinline__ void pstore(float* d, const float* s) {
    if constexpr (VEC == 4) { *(float4*)d = make_float4(s[0], s[1], s[2], s[3]); }
    else if constexpr (VEC == 2) { *(float2*)d = make_float2(s[0], s[1]); }
    else { *d = s[0]; }
}

template <int VEC, bool HASB, typename TIN, typename TOUT>
__global__ __launch_bounds__(256) void agg_kernel(
    const TIN* __restrict__ pre, const float* __restrict__ bias,
    const int* __restrict__ offsets, const int2* __restrict__ csr,
    const float* __restrict__ dinv, TOUT* __restrict__ out, int n) {
    constexpr int F = VEC * 64;
    const int wave = threadIdx.x >> 6;
    const int lane = threadIdx.x & 63;
    const int c = blockIdx.x * 4 + wave;
    if (c >= n) return;
    const float di = dinv[c];
    const float sn = di * di;
    float acc[VEC], t0[VEC], t1[VEC], t2[VEC], t3[VEC];
    pload<VEC>(acc, pre + (size_t)c * F + lane * VEC);
    #pragma unroll
    for (int v = 0; v < VEC; ++v) acc[v] *= sn;
    const int beg = offsets[c], end = offsets[c + 1];
    int j = beg;
    for (; j + 3 < end; j += 4) {
        int2 e0 = csr[j],     e1 = csr[j + 1];
        int2 e2 = csr[j + 2], e3 = csr[j + 3];
        pload<VEC>(t0, pre + (size_t)e0.x * F + lane * VEC);
        pload<VEC>(t1, pre + (size_t)e1.x * F + lane * VEC);
        pload<VEC>(t2, pre + (size_t)e2.x * F + lane * VEC);
        pload<VEC>(t3, pre + (size_t)e3.x * F + lane * VEC);
        #pragma unroll
        for (int v = 0; v < VEC; ++v) acc[v] = fmaf(__int_as_float(e0.y), t0[v], acc[v]);
        #pragma unroll
        for (int v = 0; v < VEC; ++v) acc[v] = fmaf(__int_as_float(e1.y), t1[v], acc[v]);
        #pragma unroll
        for (int v = 0; v < VEC; ++v) acc[v] = fmaf(__int_as_float(e2.y), t2[v], acc[v]);
        #pragma unroll
        for (int v = 0; v < VEC; ++v) acc[v] = fmaf(__int_as_float(e3.y), t3[v], acc[v]);
    }
    for (; j < end; ++j) {
        int2 e0 = csr[j];
        pload<VEC>(t0, pre + (size_t)e0.x * F + lane * VEC);
        #pragma unroll
        for (int v = 0; v < VEC; ++v) acc[v] = fmaf(__int_as_float(e0.y), t0[v], acc[v]);
    }
    if (HASB) {
        float bv[VEC];
        pload<VEC>(bv, bias + lane * VEC);
        #pragma unroll
        for (int v = 0; v < VEC; ++v) acc[v] += bv[v];
    }
    pstore<VEC>(out + (size_t)c * F + lane * VEC, acc);
}

// ---------------------------------------------------------------------------

extern "C" void kernel_launch(void* const* d_in, const int* in_sizes, int n_in,
                              void* d_out, int out_size, void* d_ws, size_t ws_size,
                              hipStream_t stream) {
    const float* x  = (const float*)d_in[0];
    const int*   ei = (const int*)  d_in[1];   // [2,E] int32
    const float* ew = (const float*)d_in[2];
    const float* W1 = (const float*)d_in[3];
    const float* b1 = (const float*)d_in[4];
    const float* W2 = (const float*)d_in[5];
    const float* b2 = (const float*)d_in[6];
    const float* W3 = (const float*)d_in[7];
    const float* b3 = (const float*)d_in[8];
    const float* W4 = (const float*)d_in[9];
    const float* b4 = (const float*)d_in[10];

    const int N = in_sizes[0] / IN_DIM;
    const int E = in_sizes[2];

    char* p = (char*)d_ws;
    auto alloc = [&](size_t bytes) -> void* {
        void* r = (void*)p;
        p += (bytes + 255) & ~(size_t)255;
        return r;
    };
    unsigned long long* packed = (unsigned long long*)alloc((size_t)N * 8);
    float*  dinv     = (float*)alloc((size_t)N * 4);
    int*    counts   = (int*)  alloc((size_t)N * 4);
    int*    offsets  = (int*)  alloc((size_t)(N + 1) * 4);
    int*    bsum     = (int*)  alloc((size_t)64 * 4);
    int*    rank     = (int*)  alloc((size_t)E * 4);
    int2*   csr      = (int2*) alloc((size_t)E * 8);
    __half* xh       = (__half*)alloc((size_t)N * IN_DIM * 2);  // also reused as za (same bytes)
    float*  ha       = (float*) alloc((size_t)N * IN_DIM * 4);  // also reused as P4 (same bytes)
    float*  h        = (float*) alloc((size_t)N * HID * 4);     // h1 / h3 (time-shared)
    __half* P2       = (__half*)alloc((size_t)N * LAT * 2);
    __half* zh       = (__half*)alloc((size_t)N * LAT * 2);
    float*  za       = (float*)xh;    // N*64*4 == N*128*2 bytes
    float*  P4       = ha;            // N*128*4 bytes, ha dead after L1 GEMM

    const int gN  = (N + 255) / 256;
    const int gE  = (E + 255) / 256;
    const int nbS = (N + 1023) / 1024;   // scan blocks (49 for N=50000; must be <=64)
    const int nbM = (N + 127) / 128;
    const int nodeBlocks = (N + 3) / 4;
    const int castBlocks = (N * IN_DIM / 8 + 255) / 256;

    // --- normalization + CSR build (1 atomic per edge total) ---
    k_init      <<<gN, 256, 0, stream>>>(packed, N);
    k_edge_acc  <<<gE, 256, 0, stream>>>(ei, ew, packed, rank, E);
    k_derive    <<<gN, 256, 0, stream>>>(packed, dinv, counts, N);
    k_blocksum  <<<nbS, 1024, 0, stream>>>(counts, bsum, N);
    k_scan_bsums<<<1, 64, 0, stream>>>(bsum, nbS, offsets, N);
    k_scan_apply<<<nbS, 1024, 0, stream>>>(counts, bsum, offsets, N);
    k_fill      <<<gE, 256, 0, stream>>>(ei, ew, dinv, offsets, rank, csr, E);
    k_cast      <<<castBlocks, 256, 0, stream>>>(x, xh, N * IN_DIM);

    // --- layer 1 (agg-first): ha = A_hat @ f16(x); h1 = relu(ha @ W1 + b1) ---
    agg_kernel<2, false, __half, float><<<nodeBlocks, 256, 0, stream>>>(xh, nullptr, offsets, csr, dinv, ha, N);
    gemm_mfma<128, float, true><<<dim3(nbM, HID / 128), 256, 0, stream>>>(ha, W1, b1, h, N, IN_DIM, HID);

    // --- layer 2 (gemm-first): P2 = h1 @ W2; z = A_hat @ P2 + b2 (stored f16) ---
    gemm_mfma<64, __half, false><<<dim3(nbM, LAT / 64), 256, 0, stream>>>(h, W2, nullptr, P2, N, HID, LAT);
    agg_kernel<1, true, __half, __half><<<nodeBlocks, 256, 0, stream>>>(P2, b2, offsets, csr, dinv, zh, N);

    // --- layer 3 (agg-first): za = A_hat @ zh; h3 = relu(za @ W3 + b3) ---
    agg_kernel<1, false, __half, float><<<nodeBlocks, 256, 0, stream>>>(zh, nullptr, offsets, csr, dinv, za, N);
    gemm_mfma<128, float, true><<<dim3(nbM, HID / 128), 256, 0, stream>>>(za, W3, b3, h, N, LAT, HID);

    // --- layer 4 (gemm-first, fp32 P): P4 = h3 @ W4; out = A_hat @ P4 + b4 ---
    gemm_mfma<128, float, false><<<dim3(nbM, IN_DIM / 128), 256, 0, stream>>>(h, W4, nullptr, P4, N, HID, IN_DIM);
    agg_kernel<2, true, float, float><<<nodeBlocks, 256, 0, stream>>>(P4, b4, offsets, csr, dinv, (float*)d_out, N);
}

// Round 11
// 425.947 us; speedup vs baseline: 1.9962x; 1.0354x over previous
//
#include <hip/hip_runtime.h>
#include <hip/hip_fp16.h>

#define IN_DIM 128
#define HID    256
#define LAT    64

typedef __attribute__((ext_vector_type(8))) short bf16x8;
typedef __attribute__((ext_vector_type(4))) float f32x4;

// ---------------------------------------------------------------------------
// bf16 split helpers (round-to-nearest-even)
// ---------------------------------------------------------------------------
__device__ __forceinline__ short f2bf(float f) {
    union { float f; unsigned u; } v; v.f = f;
    unsigned r = v.u + 0x7fffu + ((v.u >> 16) & 1u);
    return (short)(r >> 16);
}
__device__ __forceinline__ float bf2f(short s) {
    union { unsigned u; float f; } v; v.u = ((unsigned)(unsigned short)s) << 16;
    return v.f;
}

__device__ __forceinline__ void storeP(__half* p, float v) { *p = __float2half(v); }
__device__ __forceinline__ void storeP(float*  p, float v) { *p = v; }

// ---------------------------------------------------------------------------
// Preprocessing: packed u64 atomic (count | Q20 weight-sum) -> rank; CSR fill
// without atomics. CSR entries are int2 {row, norm-bits}.
// ---------------------------------------------------------------------------

#define FIXSCALE 1048576.0f   // 2^20

__global__ void k_init(unsigned long long* __restrict__ packed, int n) {
    int i = blockIdx.x * 256 + threadIdx.x;
    if (i < n) packed[i] = (unsigned long long)(1u << 20);   // self-loop, count 0
}

__global__ void k_edge_acc(const int* __restrict__ ei, const float* __restrict__ ew,
                           unsigned long long* __restrict__ packed,
                           int* __restrict__ rank, int E) {
    int e = blockIdx.x * 256 + threadIdx.x;
    if (e < E) {
        int c = ei[E + e];
        unsigned fx = (unsigned)lrintf(ew[e] * FIXSCALE);
        unsigned long long old =
            atomicAdd(&packed[c], ((unsigned long long)1 << 40) | (unsigned long long)fx);
        rank[e] = (int)(old >> 40);
    }
}

__global__ void k_derive(const unsigned long long* __restrict__ packed,
                         float* __restrict__ dinv, int* __restrict__ counts, int n) {
    int i = blockIdx.x * 256 + threadIdx.x;
    if (i < n) {
        unsigned long long p = packed[i];
        float deg = (float)(p & (((unsigned long long)1 << 40) - 1)) * (1.0f / FIXSCALE);
        dinv[i]   = rsqrtf(deg);           // deg >= 1 (self loop)
        counts[i] = (int)(p >> 40);
    }
}

// --- coalesced 3-phase exclusive scan (n <= 64*1024) ---
__global__ __launch_bounds__(1024) void k_blocksum(const int* __restrict__ counts,
                                                   int* __restrict__ bsum, int n) {
    __shared__ int ws[16];
    const int t = threadIdx.x, lane = t & 63, wv = t >> 6;
    int i = blockIdx.x * 1024 + t;
    int v = (i < n) ? counts[i] : 0;
    #pragma unroll
    for (int d = 1; d < 64; d <<= 1) v += __shfl_xor(v, d);
    if (lane == 0) ws[wv] = v;
    __syncthreads();
    if (wv == 0 && lane < 16) {
        int x = ws[lane];
        #pragma unroll
        for (int d = 1; d < 16; d <<= 1) x += __shfl_xor(x, d, 16);
        if (lane == 0) bsum[blockIdx.x] = x;
    }
}

__global__ void k_scan_bsums(int* __restrict__ bsum, int nb,
                             int* __restrict__ offsets, int n) {
    int lane = threadIdx.x;          // 64 threads
    int v = (lane < nb) ? bsum[lane] : 0;
    #pragma unroll
    for (int d = 1; d < 64; d <<= 1) {
        int u = __shfl_up(v, d);
        if (lane >= d) v += u;
    }
    if (lane < nb) bsum[lane] = v;   // inclusive
    if (lane == nb - 1) offsets[n] = v;
}

__global__ __launch_bounds__(1024) void k_scan_apply(const int* __restrict__ counts,
                                                     const int* __restrict__ bsum,
                                                     int* __restrict__ offsets, int n) {
    __shared__ int ws[16];
    const int t = threadIdx.x, lane = t & 63, wv = t >> 6;
    int i = blockIdx.x * 1024 + t;
    int v = (i < n) ? counts[i] : 0;
    int s = v;
    #pragma unroll
    for (int d = 1; d < 64; d <<= 1) {
        int u = __shfl_up(s, d);
        if (lane >= d) s += u;
    }
    if (lane == 63) ws[wv] = s;
    __syncthreads();
    if (wv == 0 && lane < 16) {
        int x = ws[lane];
        #pragma unroll
        for (int d = 1; d < 16; d <<= 1) {
            int u = __shfl_up(x, d, 16);
            if (lane >= d) x += u;
        }
        ws[lane] = x;
    }
    __syncthreads();
    int base = (blockIdx.x ? bsum[blockIdx.x - 1] : 0) + (wv ? ws[wv - 1] : 0);
    if (i < n) offsets[i] = base + s - v;
}

// atomic-free CSR fill: pos = offsets[col] + rank[e]; int2 {row, norm}
__global__ void k_fill(const int* __restrict__ ei, const float* __restrict__ ew,
                       const float* __restrict__ dinv, const int* __restrict__ offsets,
                       const int* __restrict__ rank,
                       int2* __restrict__ csr, int E) {
    int e = blockIdx.x * 256 + threadIdx.x;
    if (e < E) {
        int r = ei[e];
        int c = ei[E + e];
        int pos = offsets[c] + rank[e];
        float nm = dinv[r] * ew[e] * dinv[c];
        csr[pos] = make_int2(r, __float_as_int(nm));
    }
}

// fp32 -> f16 cast, 8 elems/thread (total % 8 == 0)
__global__ void k_cast(const float* __restrict__ x, __half* __restrict__ xh, int total) {
    int idx = (blockIdx.x * 256 + threadIdx.x) * 8;
    if (idx < total) {
        float4 a = *(const float4*)&x[idx];
        float4 b = *(const float4*)&x[idx + 4];
        short4 s0 = make_short4(__half_as_short(__float2half(a.x)), __half_as_short(__float2half(a.y)),
                                __half_as_short(__float2half(a.z)), __half_as_short(__float2half(a.w)));
        short4 s1 = make_short4(__half_as_short(__float2half(b.x)), __half_as_short(__float2half(b.y)),
                                __half_as_short(__float2half(b.z)), __half_as_short(__float2half(b.w)));
        *(short4*)&xh[idx]     = s0;
        *(short4*)&xh[idx + 4] = s1;
    }
}

// fp32 W -> pre-split short2{bf16 hi, bf16 lo}; bitwise-identical to in-kernel split
__global__ void k_splitW(const float* __restrict__ W, short2* __restrict__ Wsp, int total) {
    int idx = blockIdx.x * 256 + threadIdx.x;
    if (idx < total) {
        float w = W[idx];
        short h = f2bf(w);
        short l = f2bf(w - bf2f(h));
        Wsp[idx] = make_short2(h, l);
    }
}

// ---------------------------------------------------------------------------
// MFMA GEMM, bf16 Markidis split: P[M,F] = A_f32[M,K] @ W[K,F] (+b,relu).
// W arrives PRE-SPLIT as short2{hi,lo} in [K][F] layout (k_splitW).
// BM=128, BK=32, BN template (64 or 128). 256 threads = 4 waves in 2x2 grid.
// EPI=true fuses o = relu(o + bias[col]). K % 32 == 0.
// ---------------------------------------------------------------------------
template <int BN, typename PT, bool EPI>
__global__ __launch_bounds__(256) void gemm_mfma(const float* __restrict__ A,
                                                 const short2* __restrict__ Wsp,
                                                 const float* __restrict__ bias,
                                                 PT* __restrict__ P,
                                                 int M, int K, int F) {
    constexpr int WC = BN / 32;          // col fragments per wave
    __shared__ alignas(16) short Ahi[128][40];
    __shared__ alignas(16) short Alo[128][40];
    __shared__ alignas(16) short Whi[BN][40];
    __shared__ alignas(16) short Wlo[BN][40];

    const int bm  = blockIdx.x * 128;
    const int bn  = blockIdx.y * BN;
    const int tid = threadIdx.x;
    const int wv  = tid >> 6;
    const int wy  = wv >> 1;             // 0..1 : row half
    const int wx  = wv & 1;              // 0..1 : col half
    const int lane = tid & 63;
    const int frow = lane & 15;
    const int fk   = (lane >> 4) * 8;

    const int wc_ = tid % BN;
    const int kg  = tid / BN;
    constexpr int KC = 32 * BN / 256;

    f32x4 acc[4][WC];
    #pragma unroll
    for (int i = 0; i < 4; ++i)
        #pragma unroll
        for (int j = 0; j < WC; ++j)
            acc[i][j] = (f32x4){0.f, 0.f, 0.f, 0.f};

    for (int k0 = 0; k0 < K; k0 += 32) {
        if (k0) __syncthreads();
        // --- stage A: 128 rows x 32 k, float4 global loads, split to hi/lo ---
        #pragma unroll
        for (int it = 0; it < 4; ++it) {
            int l   = tid + it * 256;
            int row = l >> 3;
            int k4  = l & 7;
            int gr  = bm + row;
            float4 v = make_float4(0.f, 0.f, 0.f, 0.f);
            if (gr < M) v = *(const float4*)&A[(size_t)gr * K + k0 + k4 * 4];
            float vv[4] = {v.x, v.y, v.z, v.w};
            short h[4], lo[4];
            #pragma unroll
            for (int j = 0; j < 4; ++j) {
                h[j]  = f2bf(vv[j]);
                lo[j] = f2bf(vv[j] - bf2f(h[j]));
            }
            *(short4*)&Ahi[row][k4 * 4] = make_short4(h[0], h[1], h[2], h[3]);
            *(short4*)&Alo[row][k4 * 4] = make_short4(lo[0], lo[1], lo[2], lo[3]);
        }
        // --- stage W transposed from pre-split short2 (coalesced 4B loads) ---
        #pragma unroll
        for (int kk = 0; kk < KC; kk += 4) {
            short h[4], lo[4];
            #pragma unroll
            for (int j = 0; j < 4; ++j) {
                short2 hl = Wsp[(size_t)(k0 + kg * KC + kk + j) * F + bn + wc_];
                h[j] = hl.x; lo[j] = hl.y;
            }
            *(short4*)&Whi[wc_][kg * KC + kk] = make_short4(h[0], h[1], h[2], h[3]);
            *(short4*)&Wlo[wc_][kg * KC + kk] = make_short4(lo[0], lo[1], lo[2], lo[3]);
        }
        __syncthreads();
        bf16x8 ah[4], al[4], wh[WC], wl[WC];
        #pragma unroll
        for (int ar = 0; ar < 4; ++ar) {
            ah[ar] = *(const bf16x8*)&Ahi[wy * 64 + ar * 16 + frow][fk];
            al[ar] = *(const bf16x8*)&Alo[wy * 64 + ar * 16 + frow][fk];
        }
        #pragma unroll
        for (int wc = 0; wc < WC; ++wc) {
            wh[wc] = *(const bf16x8*)&Whi[wx * (BN / 2) + wc * 16 + frow][fk];
            wl[wc] = *(const bf16x8*)&Wlo[wx * (BN / 2) + wc * 16 + frow][fk];
        }
        #pragma unroll
        for (int ar = 0; ar < 4; ++ar)
            #pragma unroll
            for (int wc = 0; wc < WC; ++wc) {
                acc[ar][wc] = __builtin_amdgcn_mfma_f32_16x16x32_bf16(ah[ar], wh[wc], acc[ar][wc], 0, 0, 0);
                acc[ar][wc] = __builtin_amdgcn_mfma_f32_16x16x32_bf16(ah[ar], wl[wc], acc[ar][wc], 0, 0, 0);
                acc[ar][wc] = __builtin_amdgcn_mfma_f32_16x16x32_bf16(al[ar], wh[wc], acc[ar][wc], 0, 0, 0);
            }
    }
    #pragma unroll
    for (int ar = 0; ar < 4; ++ar)
        #pragma unroll
        for (int r = 0; r < 4; ++r) {
            int row = bm + wy * 64 + ar * 16 + (lane >> 4) * 4 + r;
            if (row >= M) continue;
            #pragma unroll
            for (int wc = 0; wc < WC; ++wc) {
                int col = bn + wx * (BN / 2) + wc * 16 + (lane & 15);
                float o = acc[ar][wc][r];
                if (EPI) o = fmaxf(o + bias[col], 0.f);
                storeP(&P[(size_t)row * F + col], o);
            }
        }
}

// ---------------------------------------------------------------------------
// Aggregation: out[c] = sn*self[c] + sum_e norm_e * pre[row_e] (+ bias)
// Neighbor gathers from TN* pre (f16 for traffic), self term from TS* self
// (fp32 on the output layer: sn up to ~1 passes cast error undamped).
// One wave per node, lane-vectorized (F = VEC*64); 4-edge unroll.
// ---------------------------------------------------------------------------

template <int VEC>
__device__ __forceinline__ void pload(float* d, const __half* s) {
    if constexpr (VEC == 4) {
        union { short4 s4; __half h[4]; } u;
        u.s4 = *(const short4*)s;
        #pragma unroll
        for (int j = 0; j < 4; ++j) d[j] = __half2float(u.h[j]);
    } else if constexpr (VEC == 2) {
        union { short2 s2; __half h[2]; } u;
        u.s2 = *(const short2*)s;
        d[0] = __half2float(u.h[0]); d[1] = __half2float(u.h[1]);
    } else {
        d[0] = __half2float(*s);
    }
}
template <int VEC>
__device__ __forceinline__ void pload(float* d, const float* s) {
    if constexpr (VEC == 4) { float4 v = *(const float4*)s; d[0]=v.x; d[1]=v.y; d[2]=v.z; d[3]=v.w; }
    else if constexpr (VEC == 2) { float2 v = *(const float2*)s; d[0]=v.x; d[1]=v.y; }
    else { d[0] = *s; }
}
template <int VEC>
__device__ __forceinline__ void pstore(__half* d, const float* s) {
    if constexpr (VEC == 4) {
        *(short4*)d = make_short4(__half_as_short(__float2half(s[0])), __half_as_short(__float2half(s[1])),
                                  __half_as_short(__float2half(s[2])), __half_as_short(__float2half(s[3])));
    } else if constexpr (VEC == 2) {
        *(short2*)d = make_short2(__half_as_short(__float2half(s[0])), __half_as_short(__float2half(s[1])));
    } else {
        *d = __float2half(s[0]);
    }
}
template <int VEC>
__device__ __forceinline__ void pstore(float* d, const float* s) {
    if constexpr (VEC == 4) { *(float4*)d = make_float4(s[0], s[1], s[2], s[3]); }
    else if constexpr (VEC == 2) { *(float2*)d = make_float2(s[0], s[1]); }
    else { *d = s[0]; }
}

template <int VEC, bool HASB, typename TN, typename TS, typename TOUT>
__global__ __launch_bounds__(256) void agg_kernel(
    const TN* __restrict__ pre, const TS* __restrict__ self,
    const float* __restrict__ bias,
    const int* __restrict__ offsets, const int2* __restrict__ csr,
    const float* __restrict__ dinv, TOUT* __restrict__ out, int n) {
    constexpr int F = VEC * 64;
    const int wave = threadIdx.x >> 6;
    const int lane = threadIdx.x & 63;
    const int c = blockIdx.x * 4 + wave;
    if (c >= n) return;
    const float di = dinv[c];
    const float sn = di * di;
    float acc[VEC], t0[VEC], t1[VEC], t2[VEC], t3[VEC];
    pload<VEC>(acc, self + (size_t)c * F + lane * VEC);
    #pragma unroll
    for (int v = 0; v < VEC; ++v) acc[v] *= sn;
    const int beg = offsets[c], end = offsets[c + 1];
    int j = beg;
    for (; j + 3 < end; j += 4) {
        int2 e0 = csr[j],     e1 = csr[j + 1];
        int2 e2 = csr[j + 2], e3 = csr[j + 3];
        pload<VEC>(t0, pre + (size_t)e0.x * F + lane * VEC);
        pload<VEC>(t1, pre + (size_t)e1.x * F + lane * VEC);
        pload<VEC>(t2, pre + (size_t)e2.x * F + lane * VEC);
        pload<VEC>(t3, pre + (size_t)e3.x * F + lane * VEC);
        #pragma unroll
        for (int v = 0; v < VEC; ++v) acc[v] = fmaf(__int_as_float(e0.y), t0[v], acc[v]);
        #pragma unroll
        for (int v = 0; v < VEC; ++v) acc[v] = fmaf(__int_as_float(e1.y), t1[v], acc[v]);
        #pragma unroll
        for (int v = 0; v < VEC; ++v) acc[v] = fmaf(__int_as_float(e2.y), t2[v], acc[v]);
        #pragma unroll
        for (int v = 0; v < VEC; ++v) acc[v] = fmaf(__int_as_float(e3.y), t3[v], acc[v]);
    }
    for (; j < end; ++j) {
        int2 e0 = csr[j];
        pload<VEC>(t0, pre + (size_t)e0.x * F + lane * VEC);
        #pragma unroll
        for (int v = 0; v < VEC; ++v) acc[v] = fmaf(__int_as_float(e0.y), t0[v], acc[v]);
    }
    if (HASB) {
        float bv[VEC];
        pload<VEC>(bv, bias + lane * VEC);
        #pragma unroll
        for (int v = 0; v < VEC; ++v) acc[v] += bv[v];
    }
    pstore<VEC>(out + (size_t)c * F + lane * VEC, acc);
}

// ---------------------------------------------------------------------------

extern "C" void kernel_launch(void* const* d_in, const int* in_sizes, int n_in,
                              void* d_out, int out_size, void* d_ws, size_t ws_size,
                              hipStream_t stream) {
    const float* x  = (const float*)d_in[0];
    const int*   ei = (const int*)  d_in[1];   // [2,E] int32
    const float* ew = (const float*)d_in[2];
    const float* W1 = (const float*)d_in[3];
    const float* b1 = (const float*)d_in[4];
    const float* W2 = (const float*)d_in[5];
    const float* b2 = (const float*)d_in[6];
    const float* W3 = (const float*)d_in[7];
    const float* b3 = (const float*)d_in[8];
    const float* W4 = (const float*)d_in[9];
    const float* b4 = (const float*)d_in[10];

    const int N = in_sizes[0] / IN_DIM;
    const int E = in_sizes[2];

    char* p = (char*)d_ws;
    auto alloc = [&](size_t bytes) -> void* {
        void* r = (void*)p;
        p += (bytes + 255) & ~(size_t)255;
        return r;
    };
    unsigned long long* packed = (unsigned long long*)alloc((size_t)N * 8);
    float*  dinv     = (float*)alloc((size_t)N * 4);
    int*    counts   = (int*)  alloc((size_t)N * 4);
    int*    offsets  = (int*)  alloc((size_t)(N + 1) * 4);
    int*    bsum     = (int*)  alloc((size_t)64 * 4);
    int*    rank     = (int*)  alloc((size_t)E * 4);
    int2*   csr      = (int2*) alloc((size_t)E * 8);
    short2* Wsp1     = (short2*)alloc((size_t)IN_DIM * HID * 4);
    short2* Wsp2     = (short2*)alloc((size_t)HID * LAT * 4);
    short2* Wsp3     = (short2*)alloc((size_t)LAT * HID * 4);
    short2* Wsp4     = (short2*)alloc((size_t)HID * IN_DIM * 4);
    __half* xh       = (__half*)alloc((size_t)N * IN_DIM * 2);  // reused: za (L3), P4h (L4)
    float*  ha       = (float*) alloc((size_t)N * IN_DIM * 4);  // reused: P4 (L4)
    float*  h        = (float*) alloc((size_t)N * HID * 4);     // h1 / h3 (time-shared)
    __half* P2       = (__half*)alloc((size_t)N * LAT * 2);
    __half* zh       = (__half*)alloc((size_t)N * LAT * 2);
    float*  za       = (float*)xh;    // N*64*4 == N*128*2 bytes; xh dead after L1 agg
    float*  P4       = ha;            // ha dead after L1 GEMM
    __half* P4h      = xh;            // za dead after L3 GEMM

    const int gN  = (N + 255) / 256;
    const int gE  = (E + 255) / 256;
    const int nbS = (N + 1023) / 1024;   // scan blocks (49 for N=50000; must be <=64)
    const int nbM = (N + 127) / 128;
    const int nodeBlocks = (N + 3) / 4;
    const int castBlocks = (N * IN_DIM / 8 + 255) / 256;

    // --- normalization + CSR build (1 atomic per edge total) ---
    k_init      <<<gN, 256, 0, stream>>>(packed, N);
    k_edge_acc  <<<gE, 256, 0, stream>>>(ei, ew, packed, rank, E);
    k_derive    <<<gN, 256, 0, stream>>>(packed, dinv, counts, N);
    k_blocksum  <<<nbS, 1024, 0, stream>>>(counts, bsum, N);
    k_scan_bsums<<<1, 64, 0, stream>>>(bsum, nbS, offsets, N);
    k_scan_apply<<<nbS, 1024, 0, stream>>>(counts, bsum, offsets, N);
    k_fill      <<<gE, 256, 0, stream>>>(ei, ew, dinv, offsets, rank, csr, E);
    k_cast      <<<castBlocks, 256, 0, stream>>>(x, xh, N * IN_DIM);
    k_splitW    <<<(IN_DIM * HID + 255) / 256, 256, 0, stream>>>(W1, Wsp1, IN_DIM * HID);
    k_splitW    <<<(HID * LAT + 255) / 256, 256, 0, stream>>>(W2, Wsp2, HID * LAT);
    k_splitW    <<<(LAT * HID + 255) / 256, 256, 0, stream>>>(W3, Wsp3, LAT * HID);
    k_splitW    <<<(HID * IN_DIM + 255) / 256, 256, 0, stream>>>(W4, Wsp4, HID * IN_DIM);

    // --- layer 1 (agg-first): ha = A_hat @ f16(x); h1 = relu(ha @ W1 + b1) ---
    agg_kernel<2, false, __half, __half, float><<<nodeBlocks, 256, 0, stream>>>(xh, xh, nullptr, offsets, csr, dinv, ha, N);
    gemm_mfma<128, float, true><<<dim3(nbM, HID / 128), 256, 0, stream>>>(ha, Wsp1, b1, h, N, IN_DIM, HID);

    // --- layer 2 (gemm-first): P2 = h1 @ W2; z = A_hat @ P2 + b2 (stored f16) ---
    gemm_mfma<64, __half, false><<<dim3(nbM, LAT / 64), 256, 0, stream>>>(h, Wsp2, nullptr, P2, N, HID, LAT);
    agg_kernel<1, true, __half, __half, __half><<<nodeBlocks, 256, 0, stream>>>(P2, P2, b2, offsets, csr, dinv, zh, N);

    // --- layer 3 (agg-first): za = A_hat @ zh; h3 = relu(za @ W3 + b3) ---
    agg_kernel<1, false, __half, __half, float><<<nodeBlocks, 256, 0, stream>>>(zh, zh, nullptr, offsets, csr, dinv, za, N);
    gemm_mfma<128, float, true><<<dim3(nbM, HID / 128), 256, 0, stream>>>(za, Wsp3, b3, h, N, LAT, HID);

    // --- layer 4 (gemm-first): P4 = h3 @ W4 (fp32) + f16 shadow for gathers;
    //     out = sn*P4_f32[self] + sum norm*P4h_f16[nbr] + b4 ---
    gemm_mfma<128, float, false><<<dim3(nbM, IN_DIM / 128), 256, 0, stream>>>(h, Wsp4, nullptr, P4, N, HID, IN_DIM);
    k_cast<<<castBlocks, 256, 0, stream>>>(P4, P4h, N * IN_DIM);
    agg_kernel<2, true, __half, float, float><<<nodeBlocks, 256, 0, stream>>>(P4h, P4, b4, offsets, csr, dinv, (float*)d_out, N);
}

// Round 12
// 404.811 us; speedup vs baseline: 2.1005x; 1.0522x over previous
//
#include <hip/hip_runtime.h>
#include <hip/hip_fp16.h>

#define IN_DIM 128
#define HID    256
#define LAT    64

typedef __attribute__((ext_vector_type(8))) short bf16x8;
typedef __attribute__((ext_vector_type(4))) float f32x4;

// ---------------------------------------------------------------------------
// bf16 split helpers (round-to-nearest-even)
// ---------------------------------------------------------------------------
__device__ __forceinline__ short f2bf(float f) {
    union { float f; unsigned u; } v; v.f = f;
    unsigned r = v.u + 0x7fffu + ((v.u >> 16) & 1u);
    return (short)(r >> 16);
}
__device__ __forceinline__ float bf2f(short s) {
    union { unsigned u; float f; } v; v.u = ((unsigned)(unsigned short)s) << 16;
    return v.f;
}

__device__ __forceinline__ void storeP(__half* p, float v) { *p = __float2half(v); }
__device__ __forceinline__ void storeP(float*  p, float v) { *p = v; }

// ---------------------------------------------------------------------------
// Preprocessing: packed u64 atomic (count | Q20 weight-sum) -> rank; CSR fill
// without atomics. CSR entries are int2 {row, norm-bits}.
// ---------------------------------------------------------------------------

#define FIXSCALE 1048576.0f   // 2^20

__global__ void k_init(unsigned long long* __restrict__ packed, int n) {
    int i = blockIdx.x * 256 + threadIdx.x;
    if (i < n) packed[i] = (unsigned long long)(1u << 20);   // self-loop, count 0
}

__global__ void k_edge_acc(const int* __restrict__ ei, const float* __restrict__ ew,
                           unsigned long long* __restrict__ packed,
                           int* __restrict__ rank, int E) {
    int e = blockIdx.x * 256 + threadIdx.x;
    if (e < E) {
        int c = ei[E + e];
        unsigned fx = (unsigned)lrintf(ew[e] * FIXSCALE);
        unsigned long long old =
            atomicAdd(&packed[c], ((unsigned long long)1 << 40) | (unsigned long long)fx);
        rank[e] = (int)(old >> 40);
    }
}

__global__ void k_derive(const unsigned long long* __restrict__ packed,
                         float* __restrict__ dinv, int* __restrict__ counts, int n) {
    int i = blockIdx.x * 256 + threadIdx.x;
    if (i < n) {
        unsigned long long p = packed[i];
        float deg = (float)(p & (((unsigned long long)1 << 40) - 1)) * (1.0f / FIXSCALE);
        dinv[i]   = rsqrtf(deg);           // deg >= 1 (self loop)
        counts[i] = (int)(p >> 40);
    }
}

// --- coalesced 3-phase exclusive scan (n <= 64*1024) ---
__global__ __launch_bounds__(1024) void k_blocksum(const int* __restrict__ counts,
                                                   int* __restrict__ bsum, int n) {
    __shared__ int ws[16];
    const int t = threadIdx.x, lane = t & 63, wv = t >> 6;
    int i = blockIdx.x * 1024 + t;
    int v = (i < n) ? counts[i] : 0;
    #pragma unroll
    for (int d = 1; d < 64; d <<= 1) v += __shfl_xor(v, d);
    if (lane == 0) ws[wv] = v;
    __syncthreads();
    if (wv == 0 && lane < 16) {
        int x = ws[lane];
        #pragma unroll
        for (int d = 1; d < 16; d <<= 1) x += __shfl_xor(x, d, 16);
        if (lane == 0) bsum[blockIdx.x] = x;
    }
}

__global__ void k_scan_bsums(int* __restrict__ bsum, int nb,
                             int* __restrict__ offsets, int n) {
    int lane = threadIdx.x;          // 64 threads
    int v = (lane < nb) ? bsum[lane] : 0;
    #pragma unroll
    for (int d = 1; d < 64; d <<= 1) {
        int u = __shfl_up(v, d);
        if (lane >= d) v += u;
    }
    if (lane < nb) bsum[lane] = v;   // inclusive
    if (lane == nb - 1) offsets[n] = v;
}

__global__ __launch_bounds__(1024) void k_scan_apply(const int* __restrict__ counts,
                                                     const int* __restrict__ bsum,
                                                     int* __restrict__ offsets, int n) {
    __shared__ int ws[16];
    const int t = threadIdx.x, lane = t & 63, wv = t >> 6;
    int i = blockIdx.x * 1024 + t;
    int v = (i < n) ? counts[i] : 0;
    int s = v;
    #pragma unroll
    for (int d = 1; d < 64; d <<= 1) {
        int u = __shfl_up(s, d);
        if (lane >= d) s += u;
    }
    if (lane == 63) ws[wv] = s;
    __syncthreads();
    if (wv == 0 && lane < 16) {
        int x = ws[lane];
        #pragma unroll
        for (int d = 1; d < 16; d <<= 1) {
            int u = __shfl_up(x, d, 16);
            if (lane >= d) x += u;
        }
        ws[lane] = x;
    }
    __syncthreads();
    int base = (blockIdx.x ? bsum[blockIdx.x - 1] : 0) + (wv ? ws[wv - 1] : 0);
    if (i < n) offsets[i] = base + s - v;
}

// atomic-free CSR fill: pos = offsets[col] + rank[e]; int2 {row, norm}
__global__ void k_fill(const int* __restrict__ ei, const float* __restrict__ ew,
                       const float* __restrict__ dinv, const int* __restrict__ offsets,
                       const int* __restrict__ rank,
                       int2* __restrict__ csr, int E) {
    int e = blockIdx.x * 256 + threadIdx.x;
    if (e < E) {
        int r = ei[e];
        int c = ei[E + e];
        int pos = offsets[c] + rank[e];
        float nm = dinv[r] * ew[e] * dinv[c];
        csr[pos] = make_int2(r, __float_as_int(nm));
    }
}

// fp32 -> f16 cast, 8 elems/thread (total % 8 == 0)
__global__ void k_cast(const float* __restrict__ x, __half* __restrict__ xh, int total) {
    int idx = (blockIdx.x * 256 + threadIdx.x) * 8;
    if (idx < total) {
        float4 a = *(const float4*)&x[idx];
        float4 b = *(const float4*)&x[idx + 4];
        short4 s0 = make_short4(__half_as_short(__float2half(a.x)), __half_as_short(__float2half(a.y)),
                                __half_as_short(__float2half(a.z)), __half_as_short(__float2half(a.w)));
        short4 s1 = make_short4(__half_as_short(__float2half(b.x)), __half_as_short(__float2half(b.y)),
                                __half_as_short(__float2half(b.z)), __half_as_short(__float2half(b.w)));
        *(short4*)&xh[idx]     = s0;
        *(short4*)&xh[idx + 4] = s1;
    }
}

// all 4 weight matrices -> pre-split short2{bf16 hi, bf16 lo}, one launch
__global__ void k_splitW_all(const float* __restrict__ W1, short2* __restrict__ S1, int n1,
                             const float* __restrict__ W2, short2* __restrict__ S2, int n2,
                             const float* __restrict__ W3, short2* __restrict__ S3, int n3,
                             const float* __restrict__ W4, short2* __restrict__ S4, int n4) {
    int idx = blockIdx.x * 256 + threadIdx.x;
    const float* W; short2* S;
    if (idx < n1)                { W = W1; S = S1; }
    else if (idx < n1 + n2)      { W = W2; S = S2; idx -= n1; }
    else if (idx < n1 + n2 + n3) { W = W3; S = S3; idx -= n1 + n2; }
    else if (idx < n1 + n2 + n3 + n4) { W = W4; S = S4; idx -= n1 + n2 + n3; }
    else return;
    float w = W[idx];
    short h = f2bf(w);
    short l = f2bf(w - bf2f(h));
    S[idx] = make_short2(h, l);
}

// ---------------------------------------------------------------------------
// MFMA GEMM, bf16 Markidis split: P[M,F] = A_f32[M,K] @ W[K,F] (+b,relu).
// W arrives PRE-SPLIT as short2{hi,lo} in [K][F] layout (k_splitW_all).
// BM=128, BK=32, BN template (64 or 128). 256 threads = 4 waves in 2x2 grid.
// EPI=true fuses o = relu(o + bias[col]). K % 32 == 0.
// ---------------------------------------------------------------------------
template <int BN, typename PT, bool EPI>
__global__ __launch_bounds__(256) void gemm_mfma(const float* __restrict__ A,
                                                 const short2* __restrict__ Wsp,
                                                 const float* __restrict__ bias,
                                                 PT* __restrict__ P,
                                                 int M, int K, int F) {
    constexpr int WC = BN / 32;          // col fragments per wave
    __shared__ alignas(16) short Ahi[128][40];
    __shared__ alignas(16) short Alo[128][40];
    __shared__ alignas(16) short Whi[BN][40];
    __shared__ alignas(16) short Wlo[BN][40];

    const int bm  = blockIdx.x * 128;
    const int bn  = blockIdx.y * BN;
    const int tid = threadIdx.x;
    const int wv  = tid >> 6;
    const int wy  = wv >> 1;             // 0..1 : row half
    const int wx  = wv & 1;              // 0..1 : col half
    const int lane = tid & 63;
    const int frow = lane & 15;
    const int fk   = (lane >> 4) * 8;

    const int wc_ = tid % BN;
    const int kg  = tid / BN;
    constexpr int KC = 32 * BN / 256;

    f32x4 acc[4][WC];
    #pragma unroll
    for (int i = 0; i < 4; ++i)
        #pragma unroll
        for (int j = 0; j < WC; ++j)
            acc[i][j] = (f32x4){0.f, 0.f, 0.f, 0.f};

    for (int k0 = 0; k0 < K; k0 += 32) {
        if (k0) __syncthreads();
        // --- stage A: 128 rows x 32 k, float4 global loads, split to hi/lo ---
        #pragma unroll
        for (int it = 0; it < 4; ++it) {
            int l   = tid + it * 256;
            int row = l >> 3;
            int k4  = l & 7;
            int gr  = bm + row;
            float4 v = make_float4(0.f, 0.f, 0.f, 0.f);
            if (gr < M) v = *(const float4*)&A[(size_t)gr * K + k0 + k4 * 4];
            float vv[4] = {v.x, v.y, v.z, v.w};
            short h[4], lo[4];
            #pragma unroll
            for (int j = 0; j < 4; ++j) {
                h[j]  = f2bf(vv[j]);
                lo[j] = f2bf(vv[j] - bf2f(h[j]));
            }
            *(short4*)&Ahi[row][k4 * 4] = make_short4(h[0], h[1], h[2], h[3]);
            *(short4*)&Alo[row][k4 * 4] = make_short4(lo[0], lo[1], lo[2], lo[3]);
        }
        // --- stage W transposed from pre-split short2 (coalesced 4B loads) ---
        #pragma unroll
        for (int kk = 0; kk < KC; kk += 4) {
            short h[4], lo[4];
            #pragma unroll
            for (int j = 0; j < 4; ++j) {
                short2 hl = Wsp[(size_t)(k0 + kg * KC + kk + j) * F + bn + wc_];
                h[j] = hl.x; lo[j] = hl.y;
            }
            *(short4*)&Whi[wc_][kg * KC + kk] = make_short4(h[0], h[1], h[2], h[3]);
            *(short4*)&Wlo[wc_][kg * KC + kk] = make_short4(lo[0], lo[1], lo[2], lo[3]);
        }
        __syncthreads();
        bf16x8 ah[4], al[4], wh[WC], wl[WC];
        #pragma unroll
        for (int ar = 0; ar < 4; ++ar) {
            ah[ar] = *(const bf16x8*)&Ahi[wy * 64 + ar * 16 + frow][fk];
            al[ar] = *(const bf16x8*)&Alo[wy * 64 + ar * 16 + frow][fk];
        }
        #pragma unroll
        for (int wc = 0; wc < WC; ++wc) {
            wh[wc] = *(const bf16x8*)&Whi[wx * (BN / 2) + wc * 16 + frow][fk];
            wl[wc] = *(const bf16x8*)&Wlo[wx * (BN / 2) + wc * 16 + frow][fk];
        }
        #pragma unroll
        for (int ar = 0; ar < 4; ++ar)
            #pragma unroll
            for (int wc = 0; wc < WC; ++wc) {
                acc[ar][wc] = __builtin_amdgcn_mfma_f32_16x16x32_bf16(ah[ar], wh[wc], acc[ar][wc], 0, 0, 0);
                acc[ar][wc] = __builtin_amdgcn_mfma_f32_16x16x32_bf16(ah[ar], wl[wc], acc[ar][wc], 0, 0, 0);
                acc[ar][wc] = __builtin_amdgcn_mfma_f32_16x16x32_bf16(al[ar], wh[wc], acc[ar][wc], 0, 0, 0);
            }
    }
    #pragma unroll
    for (int ar = 0; ar < 4; ++ar)
        #pragma unroll
        for (int r = 0; r < 4; ++r) {
            int row = bm + wy * 64 + ar * 16 + (lane >> 4) * 4 + r;
            if (row >= M) continue;
            #pragma unroll
            for (int wc = 0; wc < WC; ++wc) {
                int col = bn + wx * (BN / 2) + wc * 16 + (lane & 15);
                float o = acc[ar][wc][r];
                if (EPI) o = fmaxf(o + bias[col], 0.f);
                storeP(&P[(size_t)row * F + col], o);
            }
        }
}

// ---------------------------------------------------------------------------
// Aggregation: out[c] = sn*self[c] + sum_e norm_e * pre[row_e] (+ bias)
// Neighbor gathers from TN* pre (f16 for traffic), self term from TS* self.
// One wave per node, lane-vectorized (F = VEC*64); 8-edge unroll for MLP
// (latency-bound per r11 counters: HBM 35%, VALU 30%, occupancy 62%).
// ---------------------------------------------------------------------------

template <int VEC>
__device__ __forceinline__ void pload(float* d, const __half* s) {
    if constexpr (VEC == 4) {
        union { short4 s4; __half h[4]; } u;
        u.s4 = *(const short4*)s;
        #pragma unroll
        for (int j = 0; j < 4; ++j) d[j] = __half2float(u.h[j]);
    } else if constexpr (VEC == 2) {
        union { short2 s2; __half h[2]; } u;
        u.s2 = *(const short2*)s;
        d[0] = __half2float(u.h[0]); d[1] = __half2float(u.h[1]);
    } else {
        d[0] = __half2float(*s);
    }
}
template <int VEC>
__device__ __forceinline__ void pload(float* d, const float* s) {
    if constexpr (VEC == 4) { float4 v = *(const float4*)s; d[0]=v.x; d[1]=v.y; d[2]=v.z; d[3]=v.w; }
    else if constexpr (VEC == 2) { float2 v = *(const float2*)s; d[0]=v.x; d[1]=v.y; }
    else { d[0] = *s; }
}
template <int VEC>
__device__ __forceinline__ void pstore(__half* d, const float* s) {
    if constexpr (VEC == 4) {
        *(short4*)d = make_short4(__half_as_short(__float2half(s[0])), __half_as_short(__float2half(s[1])),
                                  __half_as_short(__float2half(s[2])), __half_as_short(__float2half(s[3])));
    } else if constexpr (VEC == 2) {
        *(short2*)d = make_short2(__half_as_short(__float2half(s[0])), __half_as_short(__float2half(s[1])));
    } else {
        *d = __float2half(s[0]);
    }
}
template <int VEC>
__device__ __forceinline__ void pstore(float* d, const float* s) {
    if constexpr (VEC == 4) { *(float4*)d = make_float4(s[0], s[1], s[2], s[3]); }
    else if constexpr (VEC == 2) { *(float2*)d = make_float2(s[0], s[1]); }
    else { *d = s[0]; }
}

template <int VEC, bool HASB, typename TN, typename TS, typename TOUT>
__global__ __launch_bounds__(256) void agg_kernel(
    const TN* __restrict__ pre, const TS* __restrict__ self,
    const float* __restrict__ bias,
    const int* __restrict__ offsets, const int2* __restrict__ csr,
    const float* __restrict__ dinv, TOUT* __restrict__ out, int n) {
    constexpr int F = VEC * 64;
    const int wave = threadIdx.x >> 6;
    const int lane = threadIdx.x & 63;
    const int c = blockIdx.x * 4 + wave;
    if (c >= n) return;
    const float di = dinv[c];
    const float sn = di * di;
    float acc[VEC];
    pload<VEC>(acc, self + (size_t)c * F + lane * VEC);
    #pragma unroll
    for (int v = 0; v < VEC; ++v) acc[v] *= sn;
    const int beg = offsets[c], end = offsets[c + 1];
    int j = beg;
    // 8-edge unroll: 8 independent gathers in flight per iteration
    for (; j + 7 < end; j += 8) {
        int2 e[8];
        #pragma unroll
        for (int q = 0; q < 8; ++q) e[q] = csr[j + q];
        float t[8][VEC];
        #pragma unroll
        for (int q = 0; q < 8; ++q)
            pload<VEC>(t[q], pre + (size_t)e[q].x * F + lane * VEC);
        #pragma unroll
        for (int q = 0; q < 8; ++q)
            #pragma unroll
            for (int v = 0; v < VEC; ++v)
                acc[v] = fmaf(__int_as_float(e[q].y), t[q][v], acc[v]);
    }
    for (; j + 3 < end; j += 4) {
        int2 e[4];
        #pragma unroll
        for (int q = 0; q < 4; ++q) e[q] = csr[j + q];
        float t[4][VEC];
        #pragma unroll
        for (int q = 0; q < 4; ++q)
            pload<VEC>(t[q], pre + (size_t)e[q].x * F + lane * VEC);
        #pragma unroll
        for (int q = 0; q < 4; ++q)
            #pragma unroll
            for (int v = 0; v < VEC; ++v)
                acc[v] = fmaf(__int_as_float(e[q].y), t[q][v], acc[v]);
    }
    for (; j < end; ++j) {
        int2 e0 = csr[j];
        float t0[VEC];
        pload<VEC>(t0, pre + (size_t)e0.x * F + lane * VEC);
        #pragma unroll
        for (int v = 0; v < VEC; ++v) acc[v] = fmaf(__int_as_float(e0.y), t0[v], acc[v]);
    }
    if (HASB) {
        float bv[VEC];
        pload<VEC>(bv, bias + lane * VEC);
        #pragma unroll
        for (int v = 0; v < VEC; ++v) acc[v] += bv[v];
    }
    pstore<VEC>(out + (size_t)c * F + lane * VEC, acc);
}

// ---------------------------------------------------------------------------

extern "C" void kernel_launch(void* const* d_in, const int* in_sizes, int n_in,
                              void* d_out, int out_size, void* d_ws, size_t ws_size,
                              hipStream_t stream) {
    const float* x  = (const float*)d_in[0];
    const int*   ei = (const int*)  d_in[1];   // [2,E] int32
    const float* ew = (const float*)d_in[2];
    const float* W1 = (const float*)d_in[3];
    const float* b1 = (const float*)d_in[4];
    const float* W2 = (const float*)d_in[5];
    const float* b2 = (const float*)d_in[6];
    const float* W3 = (const float*)d_in[7];
    const float* b3 = (const float*)d_in[8];
    const float* W4 = (const float*)d_in[9];
    const float* b4 = (const float*)d_in[10];

    const int N = in_sizes[0] / IN_DIM;
    const int E = in_sizes[2];

    char* p = (char*)d_ws;
    auto alloc = [&](size_t bytes) -> void* {
        void* r = (void*)p;
        p += (bytes + 255) & ~(size_t)255;
        return r;
    };
    unsigned long long* packed = (unsigned long long*)alloc((size_t)N * 8);
    float*  dinv     = (float*)alloc((size_t)N * 4);
    int*    counts   = (int*)  alloc((size_t)N * 4);
    int*    offsets  = (int*)  alloc((size_t)(N + 1) * 4);
    int*    bsum     = (int*)  alloc((size_t)64 * 4);
    int*    rank     = (int*)  alloc((size_t)E * 4);
    int2*   csr      = (int2*) alloc((size_t)E * 8);
    short2* Wsp1     = (short2*)alloc((size_t)IN_DIM * HID * 4);
    short2* Wsp2     = (short2*)alloc((size_t)HID * LAT * 4);
    short2* Wsp3     = (short2*)alloc((size_t)LAT * HID * 4);
    short2* Wsp4     = (short2*)alloc((size_t)HID * IN_DIM * 4);
    __half* xh       = (__half*)alloc((size_t)N * IN_DIM * 2);  // reused: za (L3), P4h (L4)
    float*  ha       = (float*) alloc((size_t)N * IN_DIM * 4);  // reused: P4 (L4)
    float*  h        = (float*) alloc((size_t)N * HID * 4);     // h1 / h3 (time-shared)
    __half* P2       = (__half*)alloc((size_t)N * LAT * 2);
    __half* zh       = (__half*)alloc((size_t)N * LAT * 2);
    float*  za       = (float*)xh;    // N*64*4 == N*128*2 bytes; xh dead after L1 agg
    float*  P4       = ha;            // ha dead after L1 GEMM
    __half* P4h      = xh;            // za dead after L3 GEMM

    const int gN  = (N + 255) / 256;
    const int gE  = (E + 255) / 256;
    const int nbS = (N + 1023) / 1024;   // scan blocks (49 for N=50000; must be <=64)
    const int nbM = (N + 127) / 128;
    const int nodeBlocks = (N + 3) / 4;
    const int castBlocks = (N * IN_DIM / 8 + 255) / 256;
    const int nW = IN_DIM * HID + HID * LAT + LAT * HID + HID * IN_DIM;

    // --- normalization + CSR build (1 atomic per edge total) ---
    k_init      <<<gN, 256, 0, stream>>>(packed, N);
    k_edge_acc  <<<gE, 256, 0, stream>>>(ei, ew, packed, rank, E);
    k_derive    <<<gN, 256, 0, stream>>>(packed, dinv, counts, N);
    k_blocksum  <<<nbS, 1024, 0, stream>>>(counts, bsum, N);
    k_scan_bsums<<<1, 64, 0, stream>>>(bsum, nbS, offsets, N);
    k_scan_apply<<<nbS, 1024, 0, stream>>>(counts, bsum, offsets, N);
    k_fill      <<<gE, 256, 0, stream>>>(ei, ew, dinv, offsets, rank, csr, E);
    k_cast      <<<castBlocks, 256, 0, stream>>>(x, xh, N * IN_DIM);
    k_splitW_all<<<(nW + 255) / 256, 256, 0, stream>>>(
        W1, Wsp1, IN_DIM * HID, W2, Wsp2, HID * LAT,
        W3, Wsp3, LAT * HID,   W4, Wsp4, HID * IN_DIM);

    // --- layer 1 (agg-first): ha = A_hat @ f16(x); h1 = relu(ha @ W1 + b1) ---
    agg_kernel<2, false, __half, __half, float><<<nodeBlocks, 256, 0, stream>>>(xh, xh, nullptr, offsets, csr, dinv, ha, N);
    gemm_mfma<128, float, true><<<dim3(nbM, HID / 128), 256, 0, stream>>>(ha, Wsp1, b1, h, N, IN_DIM, HID);

    // --- layer 2 (gemm-first): P2 = h1 @ W2; z = A_hat @ P2 + b2 (stored f16) ---
    gemm_mfma<64, __half, false><<<dim3(nbM, LAT / 64), 256, 0, stream>>>(h, Wsp2, nullptr, P2, N, HID, LAT);
    agg_kernel<1, true, __half, __half, __half><<<nodeBlocks, 256, 0, stream>>>(P2, P2, b2, offsets, csr, dinv, zh, N);

    // --- layer 3 (agg-first): za = A_hat @ zh; h3 = relu(za @ W3 + b3) ---
    agg_kernel<1, false, __half, __half, float><<<nodeBlocks, 256, 0, stream>>>(zh, zh, nullptr, offsets, csr, dinv, za, N);
    gemm_mfma<128, float, true><<<dim3(nbM, HID / 128), 256, 0, stream>>>(za, Wsp3, b3, h, N, LAT, HID);

    // --- layer 4 (gemm-first): P4 = h3 @ W4 (fp32) + f16 shadow for gathers;
    //     out = sn*P4_f32[self] + sum norm*P4h_f16[nbr] + b4 ---
    gemm_mfma<128, float, false><<<dim3(nbM, IN_DIM / 128), 256, 0, stream>>>(h, Wsp4, nullptr, P4, N, HID, IN_DIM);
    k_cast<<<castBlocks, 256, 0, stream>>>(P4, P4h, N * IN_DIM);
    agg_kernel<2, true, __half, float, float><<<nodeBlocks, 256, 0, stream>>>(P4h, P4, b4, offsets, csr, dinv, (float*)d_out, N);
}